// Round 17
// baseline (8280.845 us; speedup 1.0000x reference)
//
#include <hip/hip_runtime.h>
#include <hip/hip_bf16.h>
#include <stdint.h>

typedef __attribute__((ext_vector_type(8))) short short8;
typedef __attribute__((ext_vector_type(4))) float f32x4;

#define AS1 __attribute__((address_space(1)))
#define AS3 __attribute__((address_space(3)))

__device__ __forceinline__ short f2bf(float x) {
    __hip_bfloat16 h = __float2bfloat16(x);
    union { __hip_bfloat16 h; short s; } u; u.h = h; return u.s;
}

__device__ __forceinline__ void gload_lds16(const short* g, short* l) {
    __builtin_amdgcn_global_load_lds((const AS1 void*)g, (AS3 void*)l, 16, 0, 0);
}

#define SBAR()   __builtin_amdgcn_s_barrier()
#define WAITV(N) asm volatile("s_waitcnt vmcnt(" #N ")")
#define SCHED0() __builtin_amdgcn_sched_barrier(0)

// ---------------------------------------------------------------------------
// conv3 (r17): 4 blocks/CU. r15 proved occupancy is the lever (62% util at
// 3 blocks vs 45-49% at 1-2). To fit 4x in 160 KiB LDS: B taps 0/1 stay
// LDS-staged ([2][128][32] = 16 KB); tap-2's B fragments are carried in
// REGISTERS, loaded direct from global with a FULL-STEP prefetch horizon
// (~2500 cy >> 200-900 cy latency; r12's failure was a ~600 cy horizon).
// LDS = A[258][32] (16.5 KB) + B 16 KB = 32,896 B -> 33,280 alloc ->
// 4 blocks x 4 waves = 16 waves/CU (launch_bounds(256,4), VGPR ~100 <= 128).
// Step: {vmcnt0; bar; tap0/tap1 (LDS B) + tap2 (reg B); bar; STAGE(s+1);
// bT2 = Bglobal(s+1); SCHED0}. bT2 drained by next step's vmcnt(0).
// Involutions unchanged from r15 (0 conflicts measured).
// ---------------------------------------------------------------------------
__global__ __launch_bounds__(256, 4) void conv3_gemm(
    const short* __restrict__ A,        // in_pad [2*8194][4096]
    const short* __restrict__ BT,       // W2T [3][3072][4096]
    short* __restrict__ Cout,           // qkvh [16384][3072]
    const float* __restrict__ bias)     // b2 [3072]
{
    __shared__ __align__(16) short As[258 * 32];      // 16,512 B
    __shared__ __align__(16) short Bs[2 * 128 * 32];  // 16,384 B
    const int tid = threadIdx.x, lane = tid & 63, wid = tid >> 6;
    const int wm = wid >> 1, wn = wid & 1;
    const int m0 = blockIdx.y * 256, n0 = blockIdx.x * 128;
    const size_t arow0 = (size_t)(m0 >> 13) * 8194 + (size_t)(m0 & 8191);
    const short* Abase = A + arow0 * 4096;
    const short* Bbase = BT + (size_t)n0 * 4096;
    const short* B2base = BT + (size_t)2 * 3072 * 4096 + (size_t)n0 * 4096;
    const int c15 = lane & 15, g = lane >> 4, g4 = g * 4;
    const int xr0 = (c15 >> 1) & 3;
    const int xr1 = ((c15 + 1) >> 1) & 3;
    const int xr2 = ((c15 + 2) >> 1) & 3;
    const int srow = tid >> 2;
    const int schunk = (((tid & 3) ^ ((tid >> 3) & 3)) * 8);
    const int srowB = wid * 32 + (lane >> 2);
    const int schunkB = (((lane & 3) ^ ((lane >> 3) & 3)) * 8);

#define STAGE(s) do { \
    const int kc_ = (s) * 32; \
    const short* ga_ = Abase + (size_t)srow * 4096 + kc_ + schunk; \
    short* la_ = As + wid * 512; \
    gload_lds16(ga_, la_); \
    gload_lds16(ga_ + (size_t)64 * 4096, la_ + 2048); \
    gload_lds16(ga_ + (size_t)128 * 4096, la_ + 4096); \
    gload_lds16(ga_ + (size_t)192 * 4096, la_ + 6144); \
    if (wid == 3 && lane < 8) \
        gload_lds16(Abase + (size_t)(256 + (lane >> 2)) * 4096 + kc_ + (lane & 3) * 8, \
                    As + 8192); \
    _Pragma("unroll") \
    for (int tp_ = 0; tp_ < 2; ++tp_) { \
        const short* gb_ = Bbase + (size_t)tp_ * 3072 * 4096 \
                           + (size_t)srowB * 4096 + kc_ + schunkB; \
        short* lb_ = Bs + tp_ * 4096 + wid * 1024; \
        gload_lds16(gb_, lb_); \
        gload_lds16(gb_ + (size_t)16 * 4096, lb_ + 512); \
    } \
} while (0)

// tap-2 B fragment direct from global: row n0+wn*64+nj*16+c15, col s*32+g*8
#define BG2(s, nj) (*(const short8*)(B2base \
    + (size_t)(wn * 64 + (nj) * 16 + c15) * 4096 + (s) * 32 + g * 8))

#define LDA_T(mi, T, XR) (*(const short8*)(As \
    + (wm * 128 + (mi) * 16 + c15 + (T)) * 32 + ((g ^ (XR)) * 8)))
#define LDB_T(tp, nj) (*(const short8*)(Bs + (tp) * 4096 \
    + (wn * 64 + (nj) * 16 + c15) * 32 + ((g ^ xr0) * 8)))

#define MFMA_TAP(a, B0, B1, B2v, B3v, mi) do { \
    acc[mi][0] = __builtin_amdgcn_mfma_f32_16x16x32_bf16(a, B0, acc[mi][0], 0, 0, 0); \
    acc[mi][1] = __builtin_amdgcn_mfma_f32_16x16x32_bf16(a, B1, acc[mi][1], 0, 0, 0); \
    acc[mi][2] = __builtin_amdgcn_mfma_f32_16x16x32_bf16(a, B2v, acc[mi][2], 0, 0, 0); \
    acc[mi][3] = __builtin_amdgcn_mfma_f32_16x16x32_bf16(a, B3v, acc[mi][3], 0, 0, 0); \
} while (0)

    f32x4 acc[8][4];
    #pragma unroll
    for (int i = 0; i < 8; ++i)
        #pragma unroll
        for (int j = 0; j < 4; ++j)
            acc[i][j] = (f32x4){0.f, 0.f, 0.f, 0.f};

    short8 bt0, bt1, bt2, bt3;                 // tap-2 B frags (reg prefetch)
    STAGE(0);
    bt0 = BG2(0, 0); bt1 = BG2(0, 1); bt2 = BG2(0, 2); bt3 = BG2(0, 3);

    for (int s = 0; s < 128; ++s) {
        WAITV(0); SBAR(); SCHED0();            // stage(s) + bt(s) resident
        // taps 0,1 from LDS
        #pragma unroll
        for (int tp = 0; tp < 2; ++tp) {
            const int xr = (tp == 0) ? xr0 : xr1;
            short8 b0 = LDB_T(tp, 0), b1 = LDB_T(tp, 1);
            short8 b2f = LDB_T(tp, 2), b3 = LDB_T(tp, 3);
            __builtin_amdgcn_s_setprio(1);
            #pragma unroll
            for (int mi = 0; mi < 8; ++mi) {
                short8 a = LDA_T(mi, tp, xr);
                MFMA_TAP(a, b0, b1, b2f, b3, mi);
            }
            __builtin_amdgcn_s_setprio(0);
        }
        // tap 2 from registers
        __builtin_amdgcn_s_setprio(1);
        #pragma unroll
        for (int mi = 0; mi < 8; ++mi) {
            short8 a = LDA_T(mi, 2, xr2);
            MFMA_TAP(a, bt0, bt1, bt2, bt3, mi);
        }
        __builtin_amdgcn_s_setprio(0);
        SBAR();
        if (s + 1 < 128) {
            STAGE(s + 1);
            bt0 = BG2(s + 1, 0); bt1 = BG2(s + 1, 1);
            bt2 = BG2(s + 1, 2); bt3 = BG2(s + 1, 3);
            SCHED0();
        }
    }

    float bv[4];
    #pragma unroll
    for (int nj = 0; nj < 4; ++nj)
        bv[nj] = bias[n0 + wn * 64 + nj * 16 + c15];
    #pragma unroll
    for (int mi = 0; mi < 8; ++mi) {
        #pragma unroll
        for (int r = 0; r < 4; ++r) {
            const size_t row = (size_t)m0 + wm * 128 + mi * 16 + g4 + r;
            #pragma unroll
            for (int nj = 0; nj < 4; ++nj) {
                const int col = n0 + wn * 64 + nj * 16 + c15;
                Cout[row * 3072 + col] = f2bf(acc[mi][nj][r] + bv[nj]);
            }
        }
    }
#undef STAGE
#undef BG2
#undef LDA_T
#undef LDB_T
#undef MFMA_TAP
}

// ---------------------------------------------------------------------------
// gemm128 (r16): r15 structure for plain GEMMs. 256 threads (4 waves, 2x2),
// tile 256x128, BK=32, single-buffered A[256][32] + B[128][32] = 24 KB LDS.
// MODE: 0 = plain; 1 = QKVB (weight-prep: B col base += m0 & ~1023).
// ---------------------------------------------------------------------------
template<int MODE, bool F32OUT>
__global__ __launch_bounds__(256, 3) void gemm128(
    const short* __restrict__ A, int lda,
    const short* __restrict__ BT, int ldb,
    void* __restrict__ Cout, int ldc,
    const float* __restrict__ bias, int Ksteps)
{
    __shared__ __align__(16) short As[256 * 32];   // 16 KB
    __shared__ __align__(16) short Bs[128 * 32];   //  8 KB
    const int tid = threadIdx.x, lane = tid & 63, wid = tid >> 6;
    const int wm = wid >> 1, wn = wid & 1;
    const int m0 = blockIdx.y * 256, n0 = blockIdx.x * 128;
    const size_t ldaS = (size_t)lda, ldbS = (size_t)ldb;
    const short* Abase = A + (size_t)m0 * ldaS;
    const short* Bbase = BT + (size_t)n0 * ldbS + ((MODE == 1) ? (m0 & ~1023) : 0);
    const int c15 = lane & 15, g = lane >> 4, g4 = g * 4;
    const int xr0 = (c15 >> 1) & 3;
    const int srow = tid >> 2;
    const int schunk = (((tid & 3) ^ ((tid >> 3) & 3)) * 8);
    const int srowB = wid * 32 + (lane >> 2);
    const int schunkB = (((lane & 3) ^ ((lane >> 3) & 3)) * 8);

#define STG(s) do { \
    const int kc_ = (s) * 32; \
    const short* ga_ = Abase + (size_t)srow * ldaS + kc_ + schunk; \
    short* la_ = As + wid * 512; \
    gload_lds16(ga_, la_); \
    gload_lds16(ga_ + (size_t)64 * ldaS, la_ + 2048); \
    gload_lds16(ga_ + (size_t)128 * ldaS, la_ + 4096); \
    gload_lds16(ga_ + (size_t)192 * ldaS, la_ + 6144); \
    const short* gb_ = Bbase + (size_t)srowB * ldbS + kc_ + schunkB; \
    short* lb_ = Bs + wid * 1024; \
    gload_lds16(gb_, lb_); \
    gload_lds16(gb_ + (size_t)16 * ldbS, lb_ + 512); \
} while (0)

#define LDA_(mi) (*(const short8*)(As + (wm * 128 + (mi) * 16 + c15) * 32 + ((g ^ xr0) * 8)))
#define LDB_(nj) (*(const short8*)(Bs + (wn * 64 + (nj) * 16 + c15) * 32 + ((g ^ xr0) * 8)))

    f32x4 acc[8][4];
    #pragma unroll
    for (int i = 0; i < 8; ++i)
        #pragma unroll
        for (int j = 0; j < 4; ++j)
            acc[i][j] = (f32x4){0.f, 0.f, 0.f, 0.f};

    STG(0);

    for (int s = 0; s < Ksteps; ++s) {
        WAITV(0); SBAR(); SCHED0();
        short8 b0 = LDB_(0), b1 = LDB_(1), b2f = LDB_(2), b3 = LDB_(3);
        __builtin_amdgcn_s_setprio(1);
        #pragma unroll
        for (int mi = 0; mi < 8; ++mi) {
            short8 a = LDA_(mi);
            acc[mi][0] = __builtin_amdgcn_mfma_f32_16x16x32_bf16(a, b0, acc[mi][0], 0, 0, 0);
            acc[mi][1] = __builtin_amdgcn_mfma_f32_16x16x32_bf16(a, b1, acc[mi][1], 0, 0, 0);
            acc[mi][2] = __builtin_amdgcn_mfma_f32_16x16x32_bf16(a, b2f, acc[mi][2], 0, 0, 0);
            acc[mi][3] = __builtin_amdgcn_mfma_f32_16x16x32_bf16(a, b3, acc[mi][3], 0, 0, 0);
        }
        __builtin_amdgcn_s_setprio(0);
        SBAR();
        if (s + 1 < Ksteps) STG(s + 1);
    }

    float bv[4];
    #pragma unroll
    for (int nj = 0; nj < 4; ++nj)
        bv[nj] = bias ? bias[n0 + wn * 64 + nj * 16 + c15] : 0.f;
    #pragma unroll
    for (int mi = 0; mi < 8; ++mi) {
        #pragma unroll
        for (int r = 0; r < 4; ++r) {
            const size_t row = (size_t)m0 + wm * 128 + mi * 16 + g4 + r;
            #pragma unroll
            for (int nj = 0; nj < 4; ++nj) {
                const int col = n0 + wn * 64 + nj * 16 + c15;
                const float v = acc[mi][nj][r] + bv[nj];
                if (F32OUT) ((float*)Cout)[row * (size_t)ldc + col] = v;
                else        ((short*)Cout)[row * (size_t)ldc + col] = f2bf(v);
            }
        }
    }
#undef STG
#undef LDA_
#undef LDB_
}

// ---------------------------------------------------------------------------
// Per (head, block) causal attention. qkvh: [16384][3072] bf16, q at cols
// 0-1023, k at +1024, v at +2048 (col within each = h*64+e). obuf [16384][1024].
// ---------------------------------------------------------------------------
__global__ __launch_bounds__(256) void attn_kernel(
    const short* __restrict__ qkvh, short* __restrict__ obuf)
{
    __shared__ __align__(16) char smem[54272];
    short* qs = (short*)smem;                 // [128][72]
    short* ks = (short*)smem + 9216;          // [128][72]
    short* vt = (short*)(smem + 36864);       // [64][136]  (v transposed)
    short* ps = (short*)smem;                 // [128][136] (reuses qs+ks region)
    short* os = (short*)smem;                 // [128][72]  (reused post-PV)

    const int tid = threadIdx.x, lane = tid & 63, wid = tid >> 6;
    const int h = blockIdx.x, b = blockIdx.y;
    const size_t base = (size_t)b * 128 * 3072 + (size_t)h * 64;

    for (int i = tid; i < 1024; i += 256) {
        const int row = i >> 3, c8 = i & 7;
        const size_t g = base + (size_t)row * 3072 + c8 * 8;
        *(short8*)(qs + row * 72 + c8 * 8) = *(const short8*)(qkvh + g);
        *(short8*)(ks + row * 72 + c8 * 8) = *(const short8*)(qkvh + g + 1024);
        short8 vv = *(const short8*)(qkvh + g + 2048);
        #pragma unroll
        for (int j = 0; j < 8; ++j) vt[(c8 * 8 + j) * 136 + row] = vv[j];
    }
    __syncthreads();

    const int c15 = lane & 15, g8 = (lane >> 4) * 8, g4 = (lane >> 4) * 4;
    const int r0 = wid * 32;

    f32x4 sacc[2][8];
    #pragma unroll
    for (int mi = 0; mi < 2; ++mi)
        #pragma unroll
        for (int nj = 0; nj < 8; ++nj)
            sacc[mi][nj] = (f32x4){0.f, 0.f, 0.f, 0.f};
    #pragma unroll
    for (int kk = 0; kk < 2; ++kk) {
        short8 aq[2];
        #pragma unroll
        for (int mi = 0; mi < 2; ++mi)
            aq[mi] = *(const short8*)(qs + (r0 + mi * 16 + c15) * 72 + kk * 32 + g8);
        #pragma unroll
        for (int nj = 0; nj < 8; ++nj) {
            short8 bk8 = *(const short8*)(ks + (nj * 16 + c15) * 72 + kk * 32 + g8);
            #pragma unroll
            for (int mi = 0; mi < 2; ++mi)
                sacc[mi][nj] = __builtin_amdgcn_mfma_f32_16x16x32_bf16(
                    aq[mi], bk8, sacc[mi][nj], 0, 0, 0);
        }
    }
    __syncthreads();

    #pragma unroll
    for (int mi = 0; mi < 2; ++mi) {
        #pragma unroll
        for (int r = 0; r < 4; ++r) {
            const int qrow = r0 + mi * 16 + g4 + r;
            float m = -3.0e38f, pv[8];
            #pragma unroll
            for (int nj = 0; nj < 8; ++nj) {
                float s = sacc[mi][nj][r] * 0.125f;
                if (nj * 16 + c15 > qrow) s = -1.0e9f;
                pv[nj] = s; m = fmaxf(m, s);
            }
            #pragma unroll
            for (int off = 8; off >= 1; off >>= 1) m = fmaxf(m, __shfl_xor(m, off));
            float sum = 0.f;
            #pragma unroll
            for (int nj = 0; nj < 8; ++nj) { float p = __expf(pv[nj] - m); pv[nj] = p; sum += p; }
            #pragma unroll
            for (int off = 8; off >= 1; off >>= 1) sum += __shfl_xor(sum, off);
            const float inv = 1.0f / sum;
            #pragma unroll
            for (int nj = 0; nj < 8; ++nj)
                ps[qrow * 136 + nj * 16 + c15] = f2bf(pv[nj] * inv);
        }
    }
    __syncthreads();

    f32x4 oacc[2][4];
    #pragma unroll
    for (int mi = 0; mi < 2; ++mi)
        #pragma unroll
        for (int nj = 0; nj < 4; ++nj)
            oacc[mi][nj] = (f32x4){0.f, 0.f, 0.f, 0.f};
    #pragma unroll
    for (int kt = 0; kt < 4; ++kt) {
        short8 ap[2];
        #pragma unroll
        for (int mi = 0; mi < 2; ++mi)
            ap[mi] = *(const short8*)(ps + (r0 + mi * 16 + c15) * 136 + kt * 32 + g8);
        #pragma unroll
        for (int nj = 0; nj < 4; ++nj) {
            short8 bv8 = *(const short8*)(vt + (nj * 16 + c15) * 136 + kt * 32 + g8);
            #pragma unroll
            for (int mi = 0; mi < 2; ++mi)
                oacc[mi][nj] = __builtin_amdgcn_mfma_f32_16x16x32_bf16(
                    ap[mi], bv8, oacc[mi][nj], 0, 0, 0);
        }
    }
    __syncthreads();

    #pragma unroll
    for (int mi = 0; mi < 2; ++mi)
        #pragma unroll
        for (int r = 0; r < 4; ++r)
            #pragma unroll
            for (int nj = 0; nj < 4; ++nj)
                os[(r0 + mi * 16 + g4 + r) * 72 + nj * 16 + c15] = f2bf(oacc[mi][nj][r]);
    __syncthreads();

    for (int i = tid; i < 1024; i += 256) {
        const int row = i >> 3, c8 = i & 7;
        *(short8*)(obuf + (size_t)b * 128 * 1024 + (size_t)h * 64
                   + (size_t)row * 1024 + c8 * 8) =
            *(const short8*)(os + row * 72 + c8 * 8);
    }
}

// ---------------------------------------------------------------------------
__global__ void pad_convert_inputs(const float* __restrict__ in, short* __restrict__ out)
{
    const int row = blockIdx.x;                 // [0, 16388)
    const int n = row / 8194, l = row % 8194;
    short* orow = out + (size_t)row * 4096;
    if (l == 0 || l == 8193) {
        for (int i = threadIdx.x; i < 512; i += 256) {
            uint4 z; z.x = z.y = z.z = z.w = 0u;
            *(uint4*)(orow + i * 8) = z;
        }
    } else {
        const float* irow = in + ((size_t)n * 8192 + (l - 1)) * 4096;
        for (int i = threadIdx.x; i < 512; i += 256) {
            float4 a = *(const float4*)(irow + i * 8);
            float4 b = *(const float4*)(irow + i * 8 + 4);
            short8 v;
            v[0] = f2bf(a.x); v[1] = f2bf(a.y); v[2] = f2bf(a.z); v[3] = f2bf(a.w);
            v[4] = f2bf(b.x); v[5] = f2bf(b.y); v[6] = f2bf(b.z); v[7] = f2bf(b.w);
            *(short8*)(orow + i * 8) = v;
        }
    }
}

__global__ void transpose_convert(const float* __restrict__ in, short* __restrict__ out,
                                  int R, int C)
{
    __shared__ float tile[32][33];
    const int tx = threadIdx.x & 31, ty = threadIdx.x >> 5;   // 32 x 8
    const int bx = blockIdx.x * 32, by = blockIdx.y * 32;
    #pragma unroll
    for (int i = 0; i < 32; i += 8)
        tile[ty + i][tx] = in[(size_t)(by + ty + i) * C + bx + tx];
    __syncthreads();
    #pragma unroll
    for (int i = 0; i < 32; i += 8)
        out[(size_t)(bx + ty + i) * R + by + tx] = f2bf(tile[tx][ty + i]);
}

__global__ void convert_bf16(const float* __restrict__ in, short* __restrict__ out, int n8)
{
    const int idx = blockIdx.x * 256 + threadIdx.x;
    if (idx < n8) {
        float4 a = *(const float4*)(in + (size_t)idx * 8);
        float4 b = *(const float4*)(in + (size_t)idx * 8 + 4);
        short8 v;
        v[0] = f2bf(a.x); v[1] = f2bf(a.y); v[2] = f2bf(a.z); v[3] = f2bf(a.w);
        v[4] = f2bf(b.x); v[5] = f2bf(b.y); v[6] = f2bf(b.z); v[7] = f2bf(b.w);
        *(short8*)(out + (size_t)idx * 8) = v;
    }
}

__global__ void fuse_bias(const float* __restrict__ bo, const float* __restrict__ projw,
                          const float* __restrict__ projb, float* __restrict__ outb)
{
    const int j = blockIdx.x * 256 + threadIdx.x;   // 4096
    float s = projb[j];
    for (int w = 0; w < 1024; ++w) s = fmaf(bo[w], projw[(size_t)w * 4096 + j], s);
    outb[j] = s;
}

// b2[o] = b_part[o&1023] + sum_d conv_b[(o>>10)*1024+d] * wpart[d][o&1023]
__global__ void fuse_bias_qkv(const float* __restrict__ conv_b,
                              const float* __restrict__ wq, const float* __restrict__ bq,
                              const float* __restrict__ wk, const float* __restrict__ bk,
                              const float* __restrict__ wv, const float* __restrict__ bv,
                              float* __restrict__ outb)
{
    const int o = blockIdx.x * 256 + threadIdx.x;   // 3072
    const int p = o >> 10, e = o & 1023;
    const float* w = (p == 0) ? wq : (p == 1) ? wk : wv;
    const float* bb = (p == 0) ? bq : (p == 1) ? bk : bv;
    const float* cb = conv_b + p * 1024;
    float s = bb[e];
    for (int d = 0; d < 1024; ++d) s = fmaf(cb[d], w[(size_t)d * 1024 + e], s);
    outb[o] = s;
}

// ---------------------------------------------------------------------------
extern "C" void kernel_launch(void* const* d_in, const int* in_sizes, int n_in,
                              void* d_out, int out_size, void* d_ws, size_t ws_size,
                              hipStream_t stream)
{
    const float* inputs = (const float*)d_in[0];
    const float* conv_w = (const float*)d_in[1];
    const float* conv_b = (const float*)d_in[2];
    const float* wq     = (const float*)d_in[3];
    const float* bq     = (const float*)d_in[4];
    const float* wk     = (const float*)d_in[5];
    const float* bk     = (const float*)d_in[6];
    const float* wv     = (const float*)d_in[7];
    const float* bv     = (const float*)d_in[8];
    const float* wo     = (const float*)d_in[9];
    const float* bo     = (const float*)d_in[10];
    const float* proj_w = (const float*)d_in[11];
    const float* proj_b = (const float*)d_in[12];

    char* ws = (char*)d_ws;
    short* in_pad = (short*)(ws + 0);             // [2][8194][4096]      134,283,264 B
    short* cw_bf  = (short*)(ws + 134283264);     // [3][4096][3072] bf16 (dead after prep)
    short* qkvh   = (short*)(ws + 134283264);     // [16384][3072] over cw_bf
    short* W2T    = (short*)(ws + 234946560);     // [3][3072][4096] bf16
    short* wq_t   = (short*)(ws + 310444032);     // [3][1024][1024] BT contiguous
    short* wo_bf  = (short*)(ws + 316735488);     // [1024][1024]
    short* proj_t = (short*)(ws + 318832640);     // [4096][1024]
    short* WfT    = (short*)(ws + 327221248);     // [4096][1024]
    float* bfused = (float*)(ws + 335609856);     // [4096]
    float* b2     = (float*)(ws + 335626240);     // [3072]
    short* o_buf  = (short*)(ws + 0);             // [16384][1024] over in_pad

    dim3 blk(256);

    pad_convert_inputs<<<16388, blk, 0, stream>>>(inputs, in_pad);
    convert_bf16<<<18432, blk, 0, stream>>>(conv_w, cw_bf, 4718592);   // straight convert
    transpose_convert<<<dim3(32, 32), blk, 0, stream>>>(wq, wq_t, 1024, 1024);
    transpose_convert<<<dim3(32, 32), blk, 0, stream>>>(wk, wq_t + 1048576, 1024, 1024);
    transpose_convert<<<dim3(32, 32), blk, 0, stream>>>(wv, wq_t + 2097152, 1024, 1024);
    transpose_convert<<<dim3(128, 32), blk, 0, stream>>>(proj_w, proj_t, 1024, 4096);
    convert_bf16<<<512, blk, 0, stream>>>(wo, wo_bf, 131072);
    fuse_bias<<<16, blk, 0, stream>>>(bo, proj_w, proj_b, bfused);
    fuse_bias_qkv<<<12, blk, 0, stream>>>(conv_b, wq, bq, wk, bk, wv, bv, b2);

    // WfT[dm][he] = sum_w proj_t[dm][w] * wo_flat[he][w]
    gemm128<0, false><<<dim3(8, 16), blk, 0, stream>>>(
        proj_t, 1024, wo_bf, 1024, WfT, 1024, nullptr, 32);
    // weight prep: W2T[t][o][i] = sum_d wqkvT[o][d] * conv_w[t][i][(o>>10)*1024+d]
    for (int t = 0; t < 3; ++t)
        gemm128<1, false><<<dim3(32, 12), blk, 0, stream>>>(
            wq_t, 1024, cw_bf + (size_t)t * 4096 * 3072, 3072,
            W2T + (size_t)t * 3072 * 4096, 4096, nullptr, 32);
    // fused conv+projection, tap-shared A, 4 blocks/CU -> qkvh [16384][3072]
    conv3_gemm<<<dim3(24, 64), blk, 0, stream>>>(in_pad, W2T, qkvh, b2);

    attn_kernel<<<dim3(16, 128), blk, 0, stream>>>(qkvh, o_buf);

    // out = o @ Wf + bfused   (f32 out)
    gemm128<0, true><<<dim3(32, 64), blk, 0, stream>>>(
        o_buf, 1024, WfT, 1024, d_out, 4096, bfused, 32);
}

// Round 18
// 1539.454 us; speedup vs baseline: 5.3791x; 5.3791x over previous
//
#include <hip/hip_runtime.h>
#include <hip/hip_bf16.h>
#include <stdint.h>

typedef __attribute__((ext_vector_type(8))) short short8;
typedef __attribute__((ext_vector_type(4))) float f32x4;

#define AS1 __attribute__((address_space(1)))
#define AS3 __attribute__((address_space(3)))

__device__ __forceinline__ short f2bf(float x) {
    __hip_bfloat16 h = __float2bfloat16(x);
    union { __hip_bfloat16 h; short s; } u; u.h = h; return u.s;
}

__device__ __forceinline__ void gload_lds16(const short* g, short* l) {
    __builtin_amdgcn_global_load_lds((const AS1 void*)g, (AS3 void*)l, 16, 0, 0);
}

#define SBAR()   __builtin_amdgcn_s_barrier()
#define WAITV(N) asm volatile("s_waitcnt vmcnt(" #N ")")
#define SCHED0() __builtin_amdgcn_sched_barrier(0)

// ---------------------------------------------------------------------------
// conv3 (r15/r16 config, best measured: 62% MfmaUtil, 970 us): 3 blocks/CU,
// 256 threads (4 waves, 2wm x 2wn), tile 256x128, BK=32, single-buffered
// tap-shared A[258][32] + B[3][128][32] = 41 KB LDS. Cross-block MFMA/LDS
// overlap (m114) is what broke the 45-47% plateau of rounds 1-14.
// r17 lesson: 4 blocks/CU (launch_bounds(256,4)) caps regs at 128 < acc(128)
// + frags -> accumulator spill to scratch (20 GB writes, 8.5 ms). 3 blocks
// is the regfile-bounded maximum for this accumulator footprint.
// Step: {vmcnt0; bar; reads+MFMA(3 taps); bar; STAGE(s+1)}.
// Involutions as audited in r15 (0 conflicts measured).
// ---------------------------------------------------------------------------
__global__ __launch_bounds__(256, 3) void conv3_gemm(
    const short* __restrict__ A,        // in_pad [2*8194][4096]
    const short* __restrict__ BT,       // W2T [3][3072][4096]
    short* __restrict__ Cout,           // qkvh [16384][3072]
    const float* __restrict__ bias)     // b2 [3072]
{
    __shared__ __align__(16) short As[258 * 32];      // 16,512 B
    __shared__ __align__(16) short Bs[3 * 128 * 32];  // 24,576 B
    const int tid = threadIdx.x, lane = tid & 63, wid = tid >> 6;
    const int wm = wid >> 1, wn = wid & 1;
    const int m0 = blockIdx.y * 256, n0 = blockIdx.x * 128;
    const size_t arow0 = (size_t)(m0 >> 13) * 8194 + (size_t)(m0 & 8191);
    const short* Abase = A + arow0 * 4096;
    const short* Bbase = BT + (size_t)n0 * 4096;
    const int c15 = lane & 15, g = lane >> 4, g4 = g * 4;
    const int xr0 = (c15 >> 1) & 3;
    const int xr1 = ((c15 + 1) >> 1) & 3;
    const int xr2 = ((c15 + 2) >> 1) & 3;
    const int srow = tid >> 2;
    const int schunk = (((tid & 3) ^ ((tid >> 3) & 3)) * 8);
    const int srowB = wid * 32 + (lane >> 2);
    const int schunkB = (((lane & 3) ^ ((lane >> 3) & 3)) * 8);

#define STAGE(s) do { \
    const int kc_ = (s) * 32; \
    const short* ga_ = Abase + (size_t)srow * 4096 + kc_ + schunk; \
    short* la_ = As + wid * 512; \
    gload_lds16(ga_, la_); \
    gload_lds16(ga_ + (size_t)64 * 4096, la_ + 2048); \
    gload_lds16(ga_ + (size_t)128 * 4096, la_ + 4096); \
    gload_lds16(ga_ + (size_t)192 * 4096, la_ + 6144); \
    if (wid == 3 && lane < 8) \
        gload_lds16(Abase + (size_t)(256 + (lane >> 2)) * 4096 + kc_ + (lane & 3) * 8, \
                    As + 8192); \
    _Pragma("unroll") \
    for (int tp_ = 0; tp_ < 3; ++tp_) { \
        const short* gb_ = Bbase + (size_t)tp_ * 3072 * 4096 \
                           + (size_t)srowB * 4096 + kc_ + schunkB; \
        short* lb_ = Bs + tp_ * 4096 + wid * 1024; \
        gload_lds16(gb_, lb_); \
        gload_lds16(gb_ + (size_t)16 * 4096, lb_ + 512); \
    } \
} while (0)

#define LDA_T(mi, T, XR) (*(const short8*)(As \
    + (wm * 128 + (mi) * 16 + c15 + (T)) * 32 + ((g ^ (XR)) * 8)))
#define LDB_T(tp, nj) (*(const short8*)(Bs + (tp) * 4096 \
    + (wn * 64 + (nj) * 16 + c15) * 32 + ((g ^ xr0) * 8)))

    f32x4 acc[8][4];
    #pragma unroll
    for (int i = 0; i < 8; ++i)
        #pragma unroll
        for (int j = 0; j < 4; ++j)
            acc[i][j] = (f32x4){0.f, 0.f, 0.f, 0.f};

    STAGE(0);

    for (int s = 0; s < 128; ++s) {
        WAITV(0); SBAR(); SCHED0();
        #pragma unroll
        for (int tp = 0; tp < 3; ++tp) {
            const int xr = (tp == 0) ? xr0 : (tp == 1) ? xr1 : xr2;
            short8 b0 = LDB_T(tp, 0), b1 = LDB_T(tp, 1);
            short8 b2f = LDB_T(tp, 2), b3 = LDB_T(tp, 3);
            __builtin_amdgcn_s_setprio(1);
            #pragma unroll
            for (int mi = 0; mi < 8; ++mi) {
                short8 a = LDA_T(mi, tp, xr);
                acc[mi][0] = __builtin_amdgcn_mfma_f32_16x16x32_bf16(a, b0, acc[mi][0], 0, 0, 0);
                acc[mi][1] = __builtin_amdgcn_mfma_f32_16x16x32_bf16(a, b1, acc[mi][1], 0, 0, 0);
                acc[mi][2] = __builtin_amdgcn_mfma_f32_16x16x32_bf16(a, b2f, acc[mi][2], 0, 0, 0);
                acc[mi][3] = __builtin_amdgcn_mfma_f32_16x16x32_bf16(a, b3, acc[mi][3], 0, 0, 0);
            }
            __builtin_amdgcn_s_setprio(0);
        }
        SBAR();
        if (s + 1 < 128) STAGE(s + 1);
    }

    float bv[4];
    #pragma unroll
    for (int nj = 0; nj < 4; ++nj)
        bv[nj] = bias[n0 + wn * 64 + nj * 16 + c15];
    #pragma unroll
    for (int mi = 0; mi < 8; ++mi) {
        #pragma unroll
        for (int r = 0; r < 4; ++r) {
            const size_t row = (size_t)m0 + wm * 128 + mi * 16 + g4 + r;
            #pragma unroll
            for (int nj = 0; nj < 4; ++nj) {
                const int col = n0 + wn * 64 + nj * 16 + c15;
                Cout[row * 3072 + col] = f2bf(acc[mi][nj][r] + bv[nj]);
            }
        }
    }
#undef STAGE
#undef LDA_T
#undef LDB_T
}

// ---------------------------------------------------------------------------
// gemm128 (r16): r15 structure for plain GEMMs. 256 threads (4 waves, 2x2),
// tile 256x128, BK=32, single-buffered A[256][32] + B[128][32] = 24 KB LDS.
// MODE: 0 = plain; 1 = QKVB (weight-prep: B col base += m0 & ~1023).
// ---------------------------------------------------------------------------
template<int MODE, bool F32OUT>
__global__ __launch_bounds__(256, 3) void gemm128(
    const short* __restrict__ A, int lda,
    const short* __restrict__ BT, int ldb,
    void* __restrict__ Cout, int ldc,
    const float* __restrict__ bias, int Ksteps)
{
    __shared__ __align__(16) short As[256 * 32];   // 16 KB
    __shared__ __align__(16) short Bs[128 * 32];   //  8 KB
    const int tid = threadIdx.x, lane = tid & 63, wid = tid >> 6;
    const int wm = wid >> 1, wn = wid & 1;
    const int m0 = blockIdx.y * 256, n0 = blockIdx.x * 128;
    const size_t ldaS = (size_t)lda, ldbS = (size_t)ldb;
    const short* Abase = A + (size_t)m0 * ldaS;
    const short* Bbase = BT + (size_t)n0 * ldbS + ((MODE == 1) ? (m0 & ~1023) : 0);
    const int c15 = lane & 15, g = lane >> 4, g4 = g * 4;
    const int xr0 = (c15 >> 1) & 3;
    const int srow = tid >> 2;
    const int schunk = (((tid & 3) ^ ((tid >> 3) & 3)) * 8);
    const int srowB = wid * 32 + (lane >> 2);
    const int schunkB = (((lane & 3) ^ ((lane >> 3) & 3)) * 8);

#define STG(s) do { \
    const int kc_ = (s) * 32; \
    const short* ga_ = Abase + (size_t)srow * ldaS + kc_ + schunk; \
    short* la_ = As + wid * 512; \
    gload_lds16(ga_, la_); \
    gload_lds16(ga_ + (size_t)64 * ldaS, la_ + 2048); \
    gload_lds16(ga_ + (size_t)128 * ldaS, la_ + 4096); \
    gload_lds16(ga_ + (size_t)192 * ldaS, la_ + 6144); \
    const short* gb_ = Bbase + (size_t)srowB * ldbS + kc_ + schunkB; \
    short* lb_ = Bs + wid * 1024; \
    gload_lds16(gb_, lb_); \
    gload_lds16(gb_ + (size_t)16 * ldbS, lb_ + 512); \
} while (0)

#define LDA_(mi) (*(const short8*)(As + (wm * 128 + (mi) * 16 + c15) * 32 + ((g ^ xr0) * 8)))
#define LDB_(nj) (*(const short8*)(Bs + (wn * 64 + (nj) * 16 + c15) * 32 + ((g ^ xr0) * 8)))

    f32x4 acc[8][4];
    #pragma unroll
    for (int i = 0; i < 8; ++i)
        #pragma unroll
        for (int j = 0; j < 4; ++j)
            acc[i][j] = (f32x4){0.f, 0.f, 0.f, 0.f};

    STG(0);

    for (int s = 0; s < Ksteps; ++s) {
        WAITV(0); SBAR(); SCHED0();
        short8 b0 = LDB_(0), b1 = LDB_(1), b2f = LDB_(2), b3 = LDB_(3);
        __builtin_amdgcn_s_setprio(1);
        #pragma unroll
        for (int mi = 0; mi < 8; ++mi) {
            short8 a = LDA_(mi);
            acc[mi][0] = __builtin_amdgcn_mfma_f32_16x16x32_bf16(a, b0, acc[mi][0], 0, 0, 0);
            acc[mi][1] = __builtin_amdgcn_mfma_f32_16x16x32_bf16(a, b1, acc[mi][1], 0, 0, 0);
            acc[mi][2] = __builtin_amdgcn_mfma_f32_16x16x32_bf16(a, b2f, acc[mi][2], 0, 0, 0);
            acc[mi][3] = __builtin_amdgcn_mfma_f32_16x16x32_bf16(a, b3, acc[mi][3], 0, 0, 0);
        }
        __builtin_amdgcn_s_setprio(0);
        SBAR();
        if (s + 1 < Ksteps) STG(s + 1);
    }

    float bv[4];
    #pragma unroll
    for (int nj = 0; nj < 4; ++nj)
        bv[nj] = bias ? bias[n0 + wn * 64 + nj * 16 + c15] : 0.f;
    #pragma unroll
    for (int mi = 0; mi < 8; ++mi) {
        #pragma unroll
        for (int r = 0; r < 4; ++r) {
            const size_t row = (size_t)m0 + wm * 128 + mi * 16 + g4 + r;
            #pragma unroll
            for (int nj = 0; nj < 4; ++nj) {
                const int col = n0 + wn * 64 + nj * 16 + c15;
                const float v = acc[mi][nj][r] + bv[nj];
                if (F32OUT) ((float*)Cout)[row * (size_t)ldc + col] = v;
                else        ((short*)Cout)[row * (size_t)ldc + col] = f2bf(v);
            }
        }
    }
#undef STG
#undef LDA_
#undef LDB_
}

// ---------------------------------------------------------------------------
// Per (head, block) causal attention. qkvh: [16384][3072] bf16, q at cols
// 0-1023, k at +1024, v at +2048 (col within each = h*64+e). obuf [16384][1024].
// ---------------------------------------------------------------------------
__global__ __launch_bounds__(256) void attn_kernel(
    const short* __restrict__ qkvh, short* __restrict__ obuf)
{
    __shared__ __align__(16) char smem[54272];
    short* qs = (short*)smem;                 // [128][72]
    short* ks = (short*)smem + 9216;          // [128][72]
    short* vt = (short*)(smem + 36864);       // [64][136]  (v transposed)
    short* ps = (short*)smem;                 // [128][136] (reuses qs+ks region)
    short* os = (short*)smem;                 // [128][72]  (reused post-PV)

    const int tid = threadIdx.x, lane = tid & 63, wid = tid >> 6;
    const int h = blockIdx.x, b = blockIdx.y;
    const size_t base = (size_t)b * 128 * 3072 + (size_t)h * 64;

    for (int i = tid; i < 1024; i += 256) {
        const int row = i >> 3, c8 = i & 7;
        const size_t g = base + (size_t)row * 3072 + c8 * 8;
        *(short8*)(qs + row * 72 + c8 * 8) = *(const short8*)(qkvh + g);
        *(short8*)(ks + row * 72 + c8 * 8) = *(const short8*)(qkvh + g + 1024);
        short8 vv = *(const short8*)(qkvh + g + 2048);
        #pragma unroll
        for (int j = 0; j < 8; ++j) vt[(c8 * 8 + j) * 136 + row] = vv[j];
    }
    __syncthreads();

    const int c15 = lane & 15, g8 = (lane >> 4) * 8, g4 = (lane >> 4) * 4;
    const int r0 = wid * 32;

    f32x4 sacc[2][8];
    #pragma unroll
    for (int mi = 0; mi < 2; ++mi)
        #pragma unroll
        for (int nj = 0; nj < 8; ++nj)
            sacc[mi][nj] = (f32x4){0.f, 0.f, 0.f, 0.f};
    #pragma unroll
    for (int kk = 0; kk < 2; ++kk) {
        short8 aq[2];
        #pragma unroll
        for (int mi = 0; mi < 2; ++mi)
            aq[mi] = *(const short8*)(qs + (r0 + mi * 16 + c15) * 72 + kk * 32 + g8);
        #pragma unroll
        for (int nj = 0; nj < 8; ++nj) {
            short8 bk8 = *(const short8*)(ks + (nj * 16 + c15) * 72 + kk * 32 + g8);
            #pragma unroll
            for (int mi = 0; mi < 2; ++mi)
                sacc[mi][nj] = __builtin_amdgcn_mfma_f32_16x16x32_bf16(
                    aq[mi], bk8, sacc[mi][nj], 0, 0, 0);
        }
    }
    __syncthreads();

    #pragma unroll
    for (int mi = 0; mi < 2; ++mi) {
        #pragma unroll
        for (int r = 0; r < 4; ++r) {
            const int qrow = r0 + mi * 16 + g4 + r;
            float m = -3.0e38f, pv[8];
            #pragma unroll
            for (int nj = 0; nj < 8; ++nj) {
                float s = sacc[mi][nj][r] * 0.125f;
                if (nj * 16 + c15 > qrow) s = -1.0e9f;
                pv[nj] = s; m = fmaxf(m, s);
            }
            #pragma unroll
            for (int off = 8; off >= 1; off >>= 1) m = fmaxf(m, __shfl_xor(m, off));
            float sum = 0.f;
            #pragma unroll
            for (int nj = 0; nj < 8; ++nj) { float p = __expf(pv[nj] - m); pv[nj] = p; sum += p; }
            #pragma unroll
            for (int off = 8; off >= 1; off >>= 1) sum += __shfl_xor(sum, off);
            const float inv = 1.0f / sum;
            #pragma unroll
            for (int nj = 0; nj < 8; ++nj)
                ps[qrow * 136 + nj * 16 + c15] = f2bf(pv[nj] * inv);
        }
    }
    __syncthreads();

    f32x4 oacc[2][4];
    #pragma unroll
    for (int mi = 0; mi < 2; ++mi)
        #pragma unroll
        for (int nj = 0; nj < 4; ++nj)
            oacc[mi][nj] = (f32x4){0.f, 0.f, 0.f, 0.f};
    #pragma unroll
    for (int kt = 0; kt < 4; ++kt) {
        short8 ap[2];
        #pragma unroll
        for (int mi = 0; mi < 2; ++mi)
            ap[mi] = *(const short8*)(ps + (r0 + mi * 16 + c15) * 136 + kt * 32 + g8);
        #pragma unroll
        for (int nj = 0; nj < 4; ++nj) {
            short8 bv8 = *(const short8*)(vt + (nj * 16 + c15) * 136 + kt * 32 + g8);
            #pragma unroll
            for (int mi = 0; mi < 2; ++mi)
                oacc[mi][nj] = __builtin_amdgcn_mfma_f32_16x16x32_bf16(
                    ap[mi], bv8, oacc[mi][nj], 0, 0, 0);
        }
    }
    __syncthreads();

    #pragma unroll
    for (int mi = 0; mi < 2; ++mi)
        #pragma unroll
        for (int r = 0; r < 4; ++r)
            #pragma unroll
            for (int nj = 0; nj < 4; ++nj)
                os[(r0 + mi * 16 + g4 + r) * 72 + nj * 16 + c15] = f2bf(oacc[mi][nj][r]);
    __syncthreads();

    for (int i = tid; i < 1024; i += 256) {
        const int row = i >> 3, c8 = i & 7;
        *(short8*)(obuf + (size_t)b * 128 * 1024 + (size_t)h * 64
                   + (size_t)row * 1024 + c8 * 8) =
            *(const short8*)(os + row * 72 + c8 * 8);
    }
}

// ---------------------------------------------------------------------------
__global__ void pad_convert_inputs(const float* __restrict__ in, short* __restrict__ out)
{
    const int row = blockIdx.x;                 // [0, 16388)
    const int n = row / 8194, l = row % 8194;
    short* orow = out + (size_t)row * 4096;
    if (l == 0 || l == 8193) {
        for (int i = threadIdx.x; i < 512; i += 256) {
            uint4 z; z.x = z.y = z.z = z.w = 0u;
            *(uint4*)(orow + i * 8) = z;
        }
    } else {
        const float* irow = in + ((size_t)n * 8192 + (l - 1)) * 4096;
        for (int i = threadIdx.x; i < 512; i += 256) {
            float4 a = *(const float4*)(irow + i * 8);
            float4 b = *(const float4*)(irow + i * 8 + 4);
            short8 v;
            v[0] = f2bf(a.x); v[1] = f2bf(a.y); v[2] = f2bf(a.z); v[3] = f2bf(a.w);
            v[4] = f2bf(b.x); v[5] = f2bf(b.y); v[6] = f2bf(b.z); v[7] = f2bf(b.w);
            *(short8*)(orow + i * 8) = v;
        }
    }
}

__global__ void transpose_convert(const float* __restrict__ in, short* __restrict__ out,
                                  int R, int C)
{
    __shared__ float tile[32][33];
    const int tx = threadIdx.x & 31, ty = threadIdx.x >> 5;   // 32 x 8
    const int bx = blockIdx.x * 32, by = blockIdx.y * 32;
    #pragma unroll
    for (int i = 0; i < 32; i += 8)
        tile[ty + i][tx] = in[(size_t)(by + ty + i) * C + bx + tx];
    __syncthreads();
    #pragma unroll
    for (int i = 0; i < 32; i += 8)
        out[(size_t)(bx + ty + i) * R + by + tx] = f2bf(tile[tx][ty + i]);
}

__global__ void convert_bf16(const float* __restrict__ in, short* __restrict__ out, int n8)
{
    const int idx = blockIdx.x * 256 + threadIdx.x;
    if (idx < n8) {
        float4 a = *(const float4*)(in + (size_t)idx * 8);
        float4 b = *(const float4*)(in + (size_t)idx * 8 + 4);
        short8 v;
        v[0] = f2bf(a.x); v[1] = f2bf(a.y); v[2] = f2bf(a.z); v[3] = f2bf(a.w);
        v[4] = f2bf(b.x); v[5] = f2bf(b.y); v[6] = f2bf(b.z); v[7] = f2bf(b.w);
        *(short8*)(out + (size_t)idx * 8) = v;
    }
}

__global__ void fuse_bias(const float* __restrict__ bo, const float* __restrict__ projw,
                          const float* __restrict__ projb, float* __restrict__ outb)
{
    const int j = blockIdx.x * 256 + threadIdx.x;   // 4096
    float s = projb[j];
    for (int w = 0; w < 1024; ++w) s = fmaf(bo[w], projw[(size_t)w * 4096 + j], s);
    outb[j] = s;
}

// b2[o] = b_part[o&1023] + sum_d conv_b[(o>>10)*1024+d] * wpart[d][o&1023]
__global__ void fuse_bias_qkv(const float* __restrict__ conv_b,
                              const float* __restrict__ wq, const float* __restrict__ bq,
                              const float* __restrict__ wk, const float* __restrict__ bk,
                              const float* __restrict__ wv, const float* __restrict__ bv,
                              float* __restrict__ outb)
{
    const int o = blockIdx.x * 256 + threadIdx.x;   // 3072
    const int p = o >> 10, e = o & 1023;
    const float* w = (p == 0) ? wq : (p == 1) ? wk : wv;
    const float* bb = (p == 0) ? bq : (p == 1) ? bk : bv;
    const float* cb = conv_b + p * 1024;
    float s = bb[e];
    for (int d = 0; d < 1024; ++d) s = fmaf(cb[d], w[(size_t)d * 1024 + e], s);
    outb[o] = s;
}

// ---------------------------------------------------------------------------
extern "C" void kernel_launch(void* const* d_in, const int* in_sizes, int n_in,
                              void* d_out, int out_size, void* d_ws, size_t ws_size,
                              hipStream_t stream)
{
    const float* inputs = (const float*)d_in[0];
    const float* conv_w = (const float*)d_in[1];
    const float* conv_b = (const float*)d_in[2];
    const float* wq     = (const float*)d_in[3];
    const float* bq     = (const float*)d_in[4];
    const float* wk     = (const float*)d_in[5];
    const float* bk     = (const float*)d_in[6];
    const float* wv     = (const float*)d_in[7];
    const float* bv     = (const float*)d_in[8];
    const float* wo     = (const float*)d_in[9];
    const float* bo     = (const float*)d_in[10];
    const float* proj_w = (const float*)d_in[11];
    const float* proj_b = (const float*)d_in[12];

    char* ws = (char*)d_ws;
    short* in_pad = (short*)(ws + 0);             // [2][8194][4096]      134,283,264 B
    short* cw_bf  = (short*)(ws + 134283264);     // [3][4096][3072] bf16 (dead after prep)
    short* qkvh   = (short*)(ws + 134283264);     // [16384][3072] over cw_bf
    short* W2T    = (short*)(ws + 234946560);     // [3][3072][4096] bf16
    short* wq_t   = (short*)(ws + 310444032);     // [3][1024][1024] BT contiguous
    short* wo_bf  = (short*)(ws + 316735488);     // [1024][1024]
    short* proj_t = (short*)(ws + 318832640);     // [4096][1024]
    short* WfT    = (short*)(ws + 327221248);     // [4096][1024]
    float* bfused = (float*)(ws + 335609856);     // [4096]
    float* b2     = (float*)(ws + 335626240);     // [3072]
    short* o_buf  = (short*)(ws + 0);             // [16384][1024] over in_pad

    dim3 blk(256);

    pad_convert_inputs<<<16388, blk, 0, stream>>>(inputs, in_pad);
    convert_bf16<<<18432, blk, 0, stream>>>(conv_w, cw_bf, 4718592);   // straight convert
    transpose_convert<<<dim3(32, 32), blk, 0, stream>>>(wq, wq_t, 1024, 1024);
    transpose_convert<<<dim3(32, 32), blk, 0, stream>>>(wk, wq_t + 1048576, 1024, 1024);
    transpose_convert<<<dim3(32, 32), blk, 0, stream>>>(wv, wq_t + 2097152, 1024, 1024);
    transpose_convert<<<dim3(128, 32), blk, 0, stream>>>(proj_w, proj_t, 1024, 4096);
    convert_bf16<<<512, blk, 0, stream>>>(wo, wo_bf, 131072);
    fuse_bias<<<16, blk, 0, stream>>>(bo, proj_w, proj_b, bfused);
    fuse_bias_qkv<<<12, blk, 0, stream>>>(conv_b, wq, bq, wk, bk, wv, bv, b2);

    // WfT[dm][he] = sum_w proj_t[dm][w] * wo_flat[he][w]
    gemm128<0, false><<<dim3(8, 16), blk, 0, stream>>>(
        proj_t, 1024, wo_bf, 1024, WfT, 1024, nullptr, 32);
    // weight prep: W2T[t][o][i] = sum_d wqkvT[o][d] * conv_w[t][i][(o>>10)*1024+d]
    for (int t = 0; t < 3; ++t)
        gemm128<1, false><<<dim3(32, 12), blk, 0, stream>>>(
            wq_t, 1024, cw_bf + (size_t)t * 4096 * 3072, 3072,
            W2T + (size_t)t * 3072 * 4096, 4096, nullptr, 32);
    // fused conv+projection, tap-shared A, 3 blocks/CU -> qkvh [16384][3072]
    conv3_gemm<<<dim3(24, 64), blk, 0, stream>>>(in_pad, W2T, qkvh, b2);

    attn_kernel<<<dim3(16, 128), blk, 0, stream>>>(qkvh, o_buf);

    // out = o @ Wf + bfused   (f32 out)
    gemm128<0, true><<<dim3(32, 64), blk, 0, stream>>>(
        o_buf, 1024, WfT, 1024, d_out, 4096, bfused, 32);
}

// Round 19
// 1444.229 us; speedup vs baseline: 5.7337x; 1.0659x over previous
//
#include <hip/hip_runtime.h>
#include <hip/hip_bf16.h>
#include <stdint.h>

typedef __attribute__((ext_vector_type(8))) short short8;
typedef __attribute__((ext_vector_type(4))) float f32x4;

#define AS1 __attribute__((address_space(1)))
#define AS3 __attribute__((address_space(3)))

__device__ __forceinline__ short f2bf(float x) {
    __hip_bfloat16 h = __float2bfloat16(x);
    union { __hip_bfloat16 h; short s; } u; u.h = h; return u.s;
}

__device__ __forceinline__ void gload_lds16(const short* g, short* l) {
    __builtin_amdgcn_global_load_lds((const AS1 void*)g, (AS3 void*)l, 16, 0, 0);
}

#define SBAR()   __builtin_amdgcn_s_barrier()
#define WAITV(N) asm volatile("s_waitcnt vmcnt(" #N ")")
#define SCHED0() __builtin_amdgcn_sched_barrier(0)

// ---------------------------------------------------------------------------
// conv3 (r15/r16 config, best measured: 62% MfmaUtil, ~970 us): 3 blocks/CU,
// 256 threads (4 waves, 2wm x 2wn), tile 256x128, BK=32, single-buffered
// tap-shared A[258][32] + B[3][128][32] = 41 KB LDS. Cross-block MFMA/LDS
// overlap (m114) broke the 45-47% plateau of rounds 1-14.
// r17 lesson: 4 blocks/CU caps regs at 128 < acc(128)+frags -> accumulator
// spill (20 GB scratch writes, 8.5 ms). 3 blocks is the regfile-bounded max.
// Step: {vmcnt0; bar; reads+MFMA(3 taps); bar; STAGE(s+1)}.
// Involutions as audited in r15 (0 conflicts measured).
// ---------------------------------------------------------------------------
__global__ __launch_bounds__(256, 3) void conv3_gemm(
    const short* __restrict__ A,        // in_pad [2*8194][4096]
    const short* __restrict__ BT,       // W2T [3][3072][4096]
    short* __restrict__ Cout,           // qkvh [16384][3072]
    const float* __restrict__ bias)     // b2 [3072]
{
    __shared__ __align__(16) short As[258 * 32];      // 16,512 B
    __shared__ __align__(16) short Bs[3 * 128 * 32];  // 24,576 B
    const int tid = threadIdx.x, lane = tid & 63, wid = tid >> 6;
    const int wm = wid >> 1, wn = wid & 1;
    const int m0 = blockIdx.y * 256, n0 = blockIdx.x * 128;
    const size_t arow0 = (size_t)(m0 >> 13) * 8194 + (size_t)(m0 & 8191);
    const short* Abase = A + arow0 * 4096;
    const short* Bbase = BT + (size_t)n0 * 4096;
    const int c15 = lane & 15, g = lane >> 4, g4 = g * 4;
    const int xr0 = (c15 >> 1) & 3;
    const int xr1 = ((c15 + 1) >> 1) & 3;
    const int xr2 = ((c15 + 2) >> 1) & 3;
    const int srow = tid >> 2;
    const int schunk = (((tid & 3) ^ ((tid >> 3) & 3)) * 8);
    const int srowB = wid * 32 + (lane >> 2);
    const int schunkB = (((lane & 3) ^ ((lane >> 3) & 3)) * 8);

#define STAGE(s) do { \
    const int kc_ = (s) * 32; \
    const short* ga_ = Abase + (size_t)srow * 4096 + kc_ + schunk; \
    short* la_ = As + wid * 512; \
    gload_lds16(ga_, la_); \
    gload_lds16(ga_ + (size_t)64 * 4096, la_ + 2048); \
    gload_lds16(ga_ + (size_t)128 * 4096, la_ + 4096); \
    gload_lds16(ga_ + (size_t)192 * 4096, la_ + 6144); \
    if (wid == 3 && lane < 8) \
        gload_lds16(Abase + (size_t)(256 + (lane >> 2)) * 4096 + kc_ + (lane & 3) * 8, \
                    As + 8192); \
    _Pragma("unroll") \
    for (int tp_ = 0; tp_ < 3; ++tp_) { \
        const short* gb_ = Bbase + (size_t)tp_ * 3072 * 4096 \
                           + (size_t)srowB * 4096 + kc_ + schunkB; \
        short* lb_ = Bs + tp_ * 4096 + wid * 1024; \
        gload_lds16(gb_, lb_); \
        gload_lds16(gb_ + (size_t)16 * 4096, lb_ + 512); \
    } \
} while (0)

#define LDA_T(mi, T, XR) (*(const short8*)(As \
    + (wm * 128 + (mi) * 16 + c15 + (T)) * 32 + ((g ^ (XR)) * 8)))
#define LDB_T(tp, nj) (*(const short8*)(Bs + (tp) * 4096 \
    + (wn * 64 + (nj) * 16 + c15) * 32 + ((g ^ xr0) * 8)))

    f32x4 acc[8][4];
    #pragma unroll
    for (int i = 0; i < 8; ++i)
        #pragma unroll
        for (int j = 0; j < 4; ++j)
            acc[i][j] = (f32x4){0.f, 0.f, 0.f, 0.f};

    STAGE(0);

    for (int s = 0; s < 128; ++s) {
        WAITV(0); SBAR(); SCHED0();
        #pragma unroll
        for (int tp = 0; tp < 3; ++tp) {
            const int xr = (tp == 0) ? xr0 : (tp == 1) ? xr1 : xr2;
            short8 b0 = LDB_T(tp, 0), b1 = LDB_T(tp, 1);
            short8 b2f = LDB_T(tp, 2), b3 = LDB_T(tp, 3);
            __builtin_amdgcn_s_setprio(1);
            #pragma unroll
            for (int mi = 0; mi < 8; ++mi) {
                short8 a = LDA_T(mi, tp, xr);
                acc[mi][0] = __builtin_amdgcn_mfma_f32_16x16x32_bf16(a, b0, acc[mi][0], 0, 0, 0);
                acc[mi][1] = __builtin_amdgcn_mfma_f32_16x16x32_bf16(a, b1, acc[mi][1], 0, 0, 0);
                acc[mi][2] = __builtin_amdgcn_mfma_f32_16x16x32_bf16(a, b2f, acc[mi][2], 0, 0, 0);
                acc[mi][3] = __builtin_amdgcn_mfma_f32_16x16x32_bf16(a, b3, acc[mi][3], 0, 0, 0);
            }
            __builtin_amdgcn_s_setprio(0);
        }
        SBAR();
        if (s + 1 < 128) STAGE(s + 1);
    }

    float bv[4];
    #pragma unroll
    for (int nj = 0; nj < 4; ++nj)
        bv[nj] = bias[n0 + wn * 64 + nj * 16 + c15];
    #pragma unroll
    for (int mi = 0; mi < 8; ++mi) {
        #pragma unroll
        for (int r = 0; r < 4; ++r) {
            const size_t row = (size_t)m0 + wm * 128 + mi * 16 + g4 + r;
            #pragma unroll
            for (int nj = 0; nj < 4; ++nj) {
                const int col = n0 + wn * 64 + nj * 16 + c15;
                Cout[row * 3072 + col] = f2bf(acc[mi][nj][r] + bv[nj]);
            }
        }
    }
#undef STAGE
#undef LDA_T
#undef LDB_T
}

// ---------------------------------------------------------------------------
// gemm128 (r16): r15 structure for plain GEMMs. 256 threads (4 waves, 2x2),
// tile 256x128, BK=32, single-buffered A[256][32] + B[128][32] = 24 KB LDS.
// MODE: 0 = plain; 1 = QKVB (weight-prep: B col base += m0 & ~1023).
// ---------------------------------------------------------------------------
template<int MODE, bool F32OUT>
__global__ __launch_bounds__(256, 3) void gemm128(
    const short* __restrict__ A, int lda,
    const short* __restrict__ BT, int ldb,
    void* __restrict__ Cout, int ldc,
    const float* __restrict__ bias, int Ksteps)
{
    __shared__ __align__(16) short As[256 * 32];   // 16 KB
    __shared__ __align__(16) short Bs[128 * 32];   //  8 KB
    const int tid = threadIdx.x, lane = tid & 63, wid = tid >> 6;
    const int wm = wid >> 1, wn = wid & 1;
    const int m0 = blockIdx.y * 256, n0 = blockIdx.x * 128;
    const size_t ldaS = (size_t)lda, ldbS = (size_t)ldb;
    const short* Abase = A + (size_t)m0 * ldaS;
    const short* Bbase = BT + (size_t)n0 * ldbS + ((MODE == 1) ? (m0 & ~1023) : 0);
    const int c15 = lane & 15, g = lane >> 4, g4 = g * 4;
    const int xr0 = (c15 >> 1) & 3;
    const int srow = tid >> 2;
    const int schunk = (((tid & 3) ^ ((tid >> 3) & 3)) * 8);
    const int srowB = wid * 32 + (lane >> 2);
    const int schunkB = (((lane & 3) ^ ((lane >> 3) & 3)) * 8);

#define STG(s) do { \
    const int kc_ = (s) * 32; \
    const short* ga_ = Abase + (size_t)srow * ldaS + kc_ + schunk; \
    short* la_ = As + wid * 512; \
    gload_lds16(ga_, la_); \
    gload_lds16(ga_ + (size_t)64 * ldaS, la_ + 2048); \
    gload_lds16(ga_ + (size_t)128 * ldaS, la_ + 4096); \
    gload_lds16(ga_ + (size_t)192 * ldaS, la_ + 6144); \
    const short* gb_ = Bbase + (size_t)srowB * ldbS + kc_ + schunkB; \
    short* lb_ = Bs + wid * 1024; \
    gload_lds16(gb_, lb_); \
    gload_lds16(gb_ + (size_t)16 * ldbS, lb_ + 512); \
} while (0)

#define LDA_(mi) (*(const short8*)(As + (wm * 128 + (mi) * 16 + c15) * 32 + ((g ^ xr0) * 8)))
#define LDB_(nj) (*(const short8*)(Bs + (wn * 64 + (nj) * 16 + c15) * 32 + ((g ^ xr0) * 8)))

    f32x4 acc[8][4];
    #pragma unroll
    for (int i = 0; i < 8; ++i)
        #pragma unroll
        for (int j = 0; j < 4; ++j)
            acc[i][j] = (f32x4){0.f, 0.f, 0.f, 0.f};

    STG(0);

    for (int s = 0; s < Ksteps; ++s) {
        WAITV(0); SBAR(); SCHED0();
        short8 b0 = LDB_(0), b1 = LDB_(1), b2f = LDB_(2), b3 = LDB_(3);
        __builtin_amdgcn_s_setprio(1);
        #pragma unroll
        for (int mi = 0; mi < 8; ++mi) {
            short8 a = LDA_(mi);
            acc[mi][0] = __builtin_amdgcn_mfma_f32_16x16x32_bf16(a, b0, acc[mi][0], 0, 0, 0);
            acc[mi][1] = __builtin_amdgcn_mfma_f32_16x16x32_bf16(a, b1, acc[mi][1], 0, 0, 0);
            acc[mi][2] = __builtin_amdgcn_mfma_f32_16x16x32_bf16(a, b2f, acc[mi][2], 0, 0, 0);
            acc[mi][3] = __builtin_amdgcn_mfma_f32_16x16x32_bf16(a, b3, acc[mi][3], 0, 0, 0);
        }
        __builtin_amdgcn_s_setprio(0);
        SBAR();
        if (s + 1 < Ksteps) STG(s + 1);
    }

    float bv[4];
    #pragma unroll
    for (int nj = 0; nj < 4; ++nj)
        bv[nj] = bias ? bias[n0 + wn * 64 + nj * 16 + c15] : 0.f;
    #pragma unroll
    for (int mi = 0; mi < 8; ++mi) {
        #pragma unroll
        for (int r = 0; r < 4; ++r) {
            const size_t row = (size_t)m0 + wm * 128 + mi * 16 + g4 + r;
            #pragma unroll
            for (int nj = 0; nj < 4; ++nj) {
                const int col = n0 + wn * 64 + nj * 16 + c15;
                const float v = acc[mi][nj][r] + bv[nj];
                if (F32OUT) ((float*)Cout)[row * (size_t)ldc + col] = v;
                else        ((short*)Cout)[row * (size_t)ldc + col] = f2bf(v);
            }
        }
    }
#undef STG
#undef LDA_
#undef LDB_
}

// ---------------------------------------------------------------------------
// Per (head, block) causal attention. qkvh: [16384][3072] bf16, q at cols
// 0-1023, k at +1024, v at +2048 (col within each = h*64+e). obuf [16384][1024].
// ---------------------------------------------------------------------------
__global__ __launch_bounds__(256) void attn_kernel(
    const short* __restrict__ qkvh, short* __restrict__ obuf)
{
    __shared__ __align__(16) char smem[54272];
    short* qs = (short*)smem;                 // [128][72]
    short* ks = (short*)smem + 9216;          // [128][72]
    short* vt = (short*)(smem + 36864);       // [64][136]  (v transposed)
    short* ps = (short*)smem;                 // [128][136] (reuses qs+ks region)
    short* os = (short*)smem;                 // [128][72]  (reused post-PV)

    const int tid = threadIdx.x, lane = tid & 63, wid = tid >> 6;
    const int h = blockIdx.x, b = blockIdx.y;
    const size_t base = (size_t)b * 128 * 3072 + (size_t)h * 64;

    for (int i = tid; i < 1024; i += 256) {
        const int row = i >> 3, c8 = i & 7;
        const size_t g = base + (size_t)row * 3072 + c8 * 8;
        *(short8*)(qs + row * 72 + c8 * 8) = *(const short8*)(qkvh + g);
        *(short8*)(ks + row * 72 + c8 * 8) = *(const short8*)(qkvh + g + 1024);
        short8 vv = *(const short8*)(qkvh + g + 2048);
        #pragma unroll
        for (int j = 0; j < 8; ++j) vt[(c8 * 8 + j) * 136 + row] = vv[j];
    }
    __syncthreads();

    const int c15 = lane & 15, g8 = (lane >> 4) * 8, g4 = (lane >> 4) * 4;
    const int r0 = wid * 32;

    f32x4 sacc[2][8];
    #pragma unroll
    for (int mi = 0; mi < 2; ++mi)
        #pragma unroll
        for (int nj = 0; nj < 8; ++nj)
            sacc[mi][nj] = (f32x4){0.f, 0.f, 0.f, 0.f};
    #pragma unroll
    for (int kk = 0; kk < 2; ++kk) {
        short8 aq[2];
        #pragma unroll
        for (int mi = 0; mi < 2; ++mi)
            aq[mi] = *(const short8*)(qs + (r0 + mi * 16 + c15) * 72 + kk * 32 + g8);
        #pragma unroll
        for (int nj = 0; nj < 8; ++nj) {
            short8 bk8 = *(const short8*)(ks + (nj * 16 + c15) * 72 + kk * 32 + g8);
            #pragma unroll
            for (int mi = 0; mi < 2; ++mi)
                sacc[mi][nj] = __builtin_amdgcn_mfma_f32_16x16x32_bf16(
                    aq[mi], bk8, sacc[mi][nj], 0, 0, 0);
        }
    }
    __syncthreads();

    #pragma unroll
    for (int mi = 0; mi < 2; ++mi) {
        #pragma unroll
        for (int r = 0; r < 4; ++r) {
            const int qrow = r0 + mi * 16 + g4 + r;
            float m = -3.0e38f, pv[8];
            #pragma unroll
            for (int nj = 0; nj < 8; ++nj) {
                float s = sacc[mi][nj][r] * 0.125f;
                if (nj * 16 + c15 > qrow) s = -1.0e9f;
                pv[nj] = s; m = fmaxf(m, s);
            }
            #pragma unroll
            for (int off = 8; off >= 1; off >>= 1) m = fmaxf(m, __shfl_xor(m, off));
            float sum = 0.f;
            #pragma unroll
            for (int nj = 0; nj < 8; ++nj) { float p = __expf(pv[nj] - m); pv[nj] = p; sum += p; }
            #pragma unroll
            for (int off = 8; off >= 1; off >>= 1) sum += __shfl_xor(sum, off);
            const float inv = 1.0f / sum;
            #pragma unroll
            for (int nj = 0; nj < 8; ++nj)
                ps[qrow * 136 + nj * 16 + c15] = f2bf(pv[nj] * inv);
        }
    }
    __syncthreads();

    f32x4 oacc[2][4];
    #pragma unroll
    for (int mi = 0; mi < 2; ++mi)
        #pragma unroll
        for (int nj = 0; nj < 4; ++nj)
            oacc[mi][nj] = (f32x4){0.f, 0.f, 0.f, 0.f};
    #pragma unroll
    for (int kt = 0; kt < 4; ++kt) {
        short8 ap[2];
        #pragma unroll
        for (int mi = 0; mi < 2; ++mi)
            ap[mi] = *(const short8*)(ps + (r0 + mi * 16 + c15) * 136 + kt * 32 + g8);
        #pragma unroll
        for (int nj = 0; nj < 4; ++nj) {
            short8 bv8 = *(const short8*)(vt + (nj * 16 + c15) * 136 + kt * 32 + g8);
            #pragma unroll
            for (int mi = 0; mi < 2; ++mi)
                oacc[mi][nj] = __builtin_amdgcn_mfma_f32_16x16x32_bf16(
                    ap[mi], bv8, oacc[mi][nj], 0, 0, 0);
        }
    }
    __syncthreads();

    #pragma unroll
    for (int mi = 0; mi < 2; ++mi)
        #pragma unroll
        for (int r = 0; r < 4; ++r)
            #pragma unroll
            for (int nj = 0; nj < 4; ++nj)
                os[(r0 + mi * 16 + g4 + r) * 72 + nj * 16 + c15] = f2bf(oacc[mi][nj][r]);
    __syncthreads();

    for (int i = tid; i < 1024; i += 256) {
        const int row = i >> 3, c8 = i & 7;
        *(short8*)(obuf + (size_t)b * 128 * 1024 + (size_t)h * 64
                   + (size_t)row * 1024 + c8 * 8) =
            *(const short8*)(os + row * 72 + c8 * 8);
    }
}

// ---------------------------------------------------------------------------
__global__ void pad_convert_inputs(const float* __restrict__ in, short* __restrict__ out)
{
    const int row = blockIdx.x;                 // [0, 16388)
    const int n = row / 8194, l = row % 8194;
    short* orow = out + (size_t)row * 4096;
    if (l == 0 || l == 8193) {
        for (int i = threadIdx.x; i < 512; i += 256) {
            uint4 z; z.x = z.y = z.z = z.w = 0u;
            *(uint4*)(orow + i * 8) = z;
        }
    } else {
        const float* irow = in + ((size_t)n * 8192 + (l - 1)) * 4096;
        for (int i = threadIdx.x; i < 512; i += 256) {
            float4 a = *(const float4*)(irow + i * 8);
            float4 b = *(const float4*)(irow + i * 8 + 4);
            short8 v;
            v[0] = f2bf(a.x); v[1] = f2bf(a.y); v[2] = f2bf(a.z); v[3] = f2bf(a.w);
            v[4] = f2bf(b.x); v[5] = f2bf(b.y); v[6] = f2bf(b.z); v[7] = f2bf(b.w);
            *(short8*)(orow + i * 8) = v;
        }
    }
}

__global__ void transpose_convert(const float* __restrict__ in, short* __restrict__ out,
                                  int R, int C)
{
    __shared__ float tile[32][33];
    const int tx = threadIdx.x & 31, ty = threadIdx.x >> 5;   // 32 x 8
    const int bx = blockIdx.x * 32, by = blockIdx.y * 32;
    #pragma unroll
    for (int i = 0; i < 32; i += 8)
        tile[ty + i][tx] = in[(size_t)(by + ty + i) * C + bx + tx];
    __syncthreads();
    #pragma unroll
    for (int i = 0; i < 32; i += 8)
        out[(size_t)(bx + ty + i) * R + by + tx] = f2bf(tile[tx][ty + i]);
}

__global__ void convert_bf16(const float* __restrict__ in, short* __restrict__ out, int n8)
{
    const int idx = blockIdx.x * 256 + threadIdx.x;
    if (idx < n8) {
        float4 a = *(const float4*)(in + (size_t)idx * 8);
        float4 b = *(const float4*)(in + (size_t)idx * 8 + 4);
        short8 v;
        v[0] = f2bf(a.x); v[1] = f2bf(a.y); v[2] = f2bf(a.z); v[3] = f2bf(a.w);
        v[4] = f2bf(b.x); v[5] = f2bf(b.y); v[6] = f2bf(b.z); v[7] = f2bf(b.w);
        *(short8*)(out + (size_t)idx * 8) = v;
    }
}

// bfused[j] = proj_b[j] + sum_w bo[w]*proj_w[w][j] -- split-K: 16 outputs per
// 256-thread block, 16 lanes per output (64 terms each), shfl_xor reduce
// within 16-lane groups (wave-local). Grid 256 (r19: was 16 blocks with a
// 1024-deep serial fmaf chain per thread -> latency-bound on 16 CUs).
__global__ void fuse_bias(const float* __restrict__ bo, const float* __restrict__ projw,
                          const float* __restrict__ projb, float* __restrict__ outb)
{
    const int tid = threadIdx.x;
    const int j = blockIdx.x * 16 + (tid >> 4);     // 4096 outputs
    const int sub = tid & 15;
    float s = 0.f;
    const int w0 = sub * 64;
    for (int w = w0; w < w0 + 64; ++w)
        s = fmaf(bo[w], projw[(size_t)w * 4096 + j], s);
    #pragma unroll
    for (int off = 8; off >= 1; off >>= 1) s += __shfl_xor(s, off);
    if (sub == 0) outb[j] = s + projb[j];
}

// b2[o] = b_part[o&1023] + sum_d conv_b[(o>>10)*1024+d]*wpart[d][o&1023]
// same split-K structure, grid 192.
__global__ void fuse_bias_qkv(const float* __restrict__ conv_b,
                              const float* __restrict__ wq, const float* __restrict__ bq,
                              const float* __restrict__ wk, const float* __restrict__ bk,
                              const float* __restrict__ wv, const float* __restrict__ bv,
                              float* __restrict__ outb)
{
    const int tid = threadIdx.x;
    const int o = blockIdx.x * 16 + (tid >> 4);     // 3072 outputs
    const int sub = tid & 15;
    const int p = o >> 10, e = o & 1023;
    const float* w = (p == 0) ? wq : (p == 1) ? wk : wv;
    const float* bb = (p == 0) ? bq : (p == 1) ? bk : bv;
    const float* cb = conv_b + p * 1024;
    float s = 0.f;
    const int d0 = sub * 64;
    for (int d = d0; d < d0 + 64; ++d)
        s = fmaf(cb[d], w[(size_t)d * 1024 + e], s);
    #pragma unroll
    for (int off = 8; off >= 1; off >>= 1) s += __shfl_xor(s, off);
    if (sub == 0) outb[o] = s + bb[e];
}

// ---------------------------------------------------------------------------
extern "C" void kernel_launch(void* const* d_in, const int* in_sizes, int n_in,
                              void* d_out, int out_size, void* d_ws, size_t ws_size,
                              hipStream_t stream)
{
    const float* inputs = (const float*)d_in[0];
    const float* conv_w = (const float*)d_in[1];
    const float* conv_b = (const float*)d_in[2];
    const float* wq     = (const float*)d_in[3];
    const float* bq     = (const float*)d_in[4];
    const float* wk     = (const float*)d_in[5];
    const float* bk     = (const float*)d_in[6];
    const float* wv     = (const float*)d_in[7];
    const float* bv     = (const float*)d_in[8];
    const float* wo     = (const float*)d_in[9];
    const float* bo     = (const float*)d_in[10];
    const float* proj_w = (const float*)d_in[11];
    const float* proj_b = (const float*)d_in[12];

    char* ws = (char*)d_ws;
    short* in_pad = (short*)(ws + 0);             // [2][8194][4096]      134,283,264 B
    short* cw_bf  = (short*)(ws + 134283264);     // [3][4096][3072] bf16 (dead after prep)
    short* qkvh   = (short*)(ws + 134283264);     // [16384][3072] over cw_bf
    short* W2T    = (short*)(ws + 234946560);     // [3][3072][4096] bf16
    short* wq_t   = (short*)(ws + 310444032);     // [3][1024][1024] BT contiguous
    short* wo_bf  = (short*)(ws + 316735488);     // [1024][1024]
    short* proj_t = (short*)(ws + 318832640);     // [4096][1024]
    short* WfT    = (short*)(ws + 327221248);     // [4096][1024]
    float* bfused = (float*)(ws + 335609856);     // [4096]
    float* b2     = (float*)(ws + 335626240);     // [3072]
    short* o_buf  = (short*)(ws + 0);             // [16384][1024] over in_pad

    dim3 blk(256);

    pad_convert_inputs<<<16388, blk, 0, stream>>>(inputs, in_pad);
    convert_bf16<<<18432, blk, 0, stream>>>(conv_w, cw_bf, 4718592);   // straight convert
    transpose_convert<<<dim3(32, 32), blk, 0, stream>>>(wq, wq_t, 1024, 1024);
    transpose_convert<<<dim3(32, 32), blk, 0, stream>>>(wk, wq_t + 1048576, 1024, 1024);
    transpose_convert<<<dim3(32, 32), blk, 0, stream>>>(wv, wq_t + 2097152, 1024, 1024);
    transpose_convert<<<dim3(128, 32), blk, 0, stream>>>(proj_w, proj_t, 1024, 4096);
    convert_bf16<<<512, blk, 0, stream>>>(wo, wo_bf, 131072);
    fuse_bias<<<256, blk, 0, stream>>>(bo, proj_w, proj_b, bfused);
    fuse_bias_qkv<<<192, blk, 0, stream>>>(conv_b, wq, bq, wk, bk, wv, bv, b2);

    // WfT[dm][he] = sum_w proj_t[dm][w] * wo_flat[he][w]
    gemm128<0, false><<<dim3(8, 16), blk, 0, stream>>>(
        proj_t, 1024, wo_bf, 1024, WfT, 1024, nullptr, 32);
    // weight prep: W2T[t][o][i] = sum_d wqkvT[o][d] * conv_w[t][i][(o>>10)*1024+d]
    for (int t = 0; t < 3; ++t)
        gemm128<1, false><<<dim3(32, 12), blk, 0, stream>>>(
            wq_t, 1024, cw_bf + (size_t)t * 4096 * 3072, 3072,
            W2T + (size_t)t * 3072 * 4096, 4096, nullptr, 32);
    // fused conv+projection, tap-shared A, 3 blocks/CU -> qkvh [16384][3072]
    conv3_gemm<<<dim3(24, 64), blk, 0, stream>>>(in_pad, W2T, qkvh, b2);

    attn_kernel<<<dim3(16, 128), blk, 0, stream>>>(qkvh, o_buf);

    // out = o @ Wf + bfused   (f32 out)
    gemm128<0, true><<<dim3(32, 64), blk, 0, stream>>>(
        o_buf, 1024, WfT, 1024, d_out, 4096, bfused, 32);
}

// Round 20
// 1420.163 us; speedup vs baseline: 5.8309x; 1.0169x over previous
//
#include <hip/hip_runtime.h>
#include <hip/hip_bf16.h>
#include <stdint.h>

typedef __attribute__((ext_vector_type(8))) short short8;
typedef __attribute__((ext_vector_type(4))) float f32x4;

#define AS1 __attribute__((address_space(1)))
#define AS3 __attribute__((address_space(3)))

__device__ __forceinline__ short f2bf(float x) {
    __hip_bfloat16 h = __float2bfloat16(x);
    union { __hip_bfloat16 h; short s; } u; u.h = h; return u.s;
}

__device__ __forceinline__ void gload_lds16(const short* g, short* l) {
    __builtin_amdgcn_global_load_lds((const AS1 void*)g, (AS3 void*)l, 16, 0, 0);
}

#define SBAR()   __builtin_amdgcn_s_barrier()
#define WAITV(N) asm volatile("s_waitcnt vmcnt(" #N ")")
#define SCHED0() __builtin_amdgcn_sched_barrier(0)

// ---------------------------------------------------------------------------
// conv3 (r15/r16 config, best measured: 62% MfmaUtil, ~970 us): 3 blocks/CU,
// 256 threads (4 waves, 2wm x 2wn), tile 256x128, BK=32, single-buffered
// tap-shared A[258][32] + B[3][128][32] = 41 KB LDS. Cross-block MFMA/LDS
// overlap (m114) broke the 45-47% plateau of rounds 1-14.
// r17 lesson: 4 blocks/CU caps regs at 128 < acc(128)+frags -> accumulator
// spill (20 GB scratch writes, 8.5 ms). 3 blocks is the regfile-bounded max.
// Step: {vmcnt0; bar; reads+MFMA(3 taps); bar; STAGE(s+1)}.
// Involutions as audited in r15 (0 conflicts measured).
// ---------------------------------------------------------------------------
__global__ __launch_bounds__(256, 3) void conv3_gemm(
    const short* __restrict__ A,        // in_pad [2*8194][4096]
    const short* __restrict__ BT,       // W2T [3][3072][4096]
    short* __restrict__ Cout,           // qkvh [16384][3072]
    const float* __restrict__ bias)     // b2 [3072]
{
    __shared__ __align__(16) short As[258 * 32];      // 16,512 B
    __shared__ __align__(16) short Bs[3 * 128 * 32];  // 24,576 B
    const int tid = threadIdx.x, lane = tid & 63, wid = tid >> 6;
    const int wm = wid >> 1, wn = wid & 1;
    const int m0 = blockIdx.y * 256, n0 = blockIdx.x * 128;
    const size_t arow0 = (size_t)(m0 >> 13) * 8194 + (size_t)(m0 & 8191);
    const short* Abase = A + arow0 * 4096;
    const short* Bbase = BT + (size_t)n0 * 4096;
    const int c15 = lane & 15, g = lane >> 4, g4 = g * 4;
    const int xr0 = (c15 >> 1) & 3;
    const int xr1 = ((c15 + 1) >> 1) & 3;
    const int xr2 = ((c15 + 2) >> 1) & 3;
    const int srow = tid >> 2;
    const int schunk = (((tid & 3) ^ ((tid >> 3) & 3)) * 8);
    const int srowB = wid * 32 + (lane >> 2);
    const int schunkB = (((lane & 3) ^ ((lane >> 3) & 3)) * 8);

#define STAGE(s) do { \
    const int kc_ = (s) * 32; \
    const short* ga_ = Abase + (size_t)srow * 4096 + kc_ + schunk; \
    short* la_ = As + wid * 512; \
    gload_lds16(ga_, la_); \
    gload_lds16(ga_ + (size_t)64 * 4096, la_ + 2048); \
    gload_lds16(ga_ + (size_t)128 * 4096, la_ + 4096); \
    gload_lds16(ga_ + (size_t)192 * 4096, la_ + 6144); \
    if (wid == 3 && lane < 8) \
        gload_lds16(Abase + (size_t)(256 + (lane >> 2)) * 4096 + kc_ + (lane & 3) * 8, \
                    As + 8192); \
    _Pragma("unroll") \
    for (int tp_ = 0; tp_ < 3; ++tp_) { \
        const short* gb_ = Bbase + (size_t)tp_ * 3072 * 4096 \
                           + (size_t)srowB * 4096 + kc_ + schunkB; \
        short* lb_ = Bs + tp_ * 4096 + wid * 1024; \
        gload_lds16(gb_, lb_); \
        gload_lds16(gb_ + (size_t)16 * 4096, lb_ + 512); \
    } \
} while (0)

#define LDA_T(mi, T, XR) (*(const short8*)(As \
    + (wm * 128 + (mi) * 16 + c15 + (T)) * 32 + ((g ^ (XR)) * 8)))
#define LDB_T(tp, nj) (*(const short8*)(Bs + (tp) * 4096 \
    + (wn * 64 + (nj) * 16 + c15) * 32 + ((g ^ xr0) * 8)))

    f32x4 acc[8][4];
    #pragma unroll
    for (int i = 0; i < 8; ++i)
        #pragma unroll
        for (int j = 0; j < 4; ++j)
            acc[i][j] = (f32x4){0.f, 0.f, 0.f, 0.f};

    STAGE(0);

    for (int s = 0; s < 128; ++s) {
        WAITV(0); SBAR(); SCHED0();
        #pragma unroll
        for (int tp = 0; tp < 3; ++tp) {
            const int xr = (tp == 0) ? xr0 : (tp == 1) ? xr1 : xr2;
            short8 b0 = LDB_T(tp, 0), b1 = LDB_T(tp, 1);
            short8 b2f = LDB_T(tp, 2), b3 = LDB_T(tp, 3);
            __builtin_amdgcn_s_setprio(1);
            #pragma unroll
            for (int mi = 0; mi < 8; ++mi) {
                short8 a = LDA_T(mi, tp, xr);
                acc[mi][0] = __builtin_amdgcn_mfma_f32_16x16x32_bf16(a, b0, acc[mi][0], 0, 0, 0);
                acc[mi][1] = __builtin_amdgcn_mfma_f32_16x16x32_bf16(a, b1, acc[mi][1], 0, 0, 0);
                acc[mi][2] = __builtin_amdgcn_mfma_f32_16x16x32_bf16(a, b2f, acc[mi][2], 0, 0, 0);
                acc[mi][3] = __builtin_amdgcn_mfma_f32_16x16x32_bf16(a, b3, acc[mi][3], 0, 0, 0);
            }
            __builtin_amdgcn_s_setprio(0);
        }
        SBAR();
        if (s + 1 < 128) STAGE(s + 1);
    }

    float bv[4];
    #pragma unroll
    for (int nj = 0; nj < 4; ++nj)
        bv[nj] = bias[n0 + wn * 64 + nj * 16 + c15];
    #pragma unroll
    for (int mi = 0; mi < 8; ++mi) {
        #pragma unroll
        for (int r = 0; r < 4; ++r) {
            const size_t row = (size_t)m0 + wm * 128 + mi * 16 + g4 + r;
            #pragma unroll
            for (int nj = 0; nj < 4; ++nj) {
                const int col = n0 + wn * 64 + nj * 16 + c15;
                Cout[row * 3072 + col] = f2bf(acc[mi][nj][r] + bv[nj]);
            }
        }
    }
#undef STAGE
#undef LDA_T
#undef LDB_T
}

// ---------------------------------------------------------------------------
// gemm128 (r16): r15 structure for plain GEMMs. 256 threads (4 waves, 2x2),
// tile 256x128, BK=32, single-buffered A[256][32] + B[128][32] = 24 KB LDS.
// MODE: 0 = plain; 1 = QKVB (B col base += m0 & ~1023);
//       2 = QKVB + blockIdx.z tap (BT/Cout += z * 12,582,912 elems; r20:
//           merges the 3 W2T prep dispatches into one 1152-block launch).
// ---------------------------------------------------------------------------
template<int MODE, bool F32OUT>
__global__ __launch_bounds__(256, 3) void gemm128(
    const short* __restrict__ A, int lda,
    const short* __restrict__ BT, int ldb,
    void* __restrict__ Cout, int ldc,
    const float* __restrict__ bias, int Ksteps)
{
    __shared__ __align__(16) short As[256 * 32];   // 16 KB
    __shared__ __align__(16) short Bs[128 * 32];   //  8 KB
    const int tid = threadIdx.x, lane = tid & 63, wid = tid >> 6;
    const int wm = wid >> 1, wn = wid & 1;
    const int m0 = blockIdx.y * 256, n0 = blockIdx.x * 128;
    const size_t ldaS = (size_t)lda, ldbS = (size_t)ldb;
    const size_t zoff = (MODE == 2) ? (size_t)blockIdx.z * 12582912 : 0;
    const short* Abase = A + (size_t)m0 * ldaS;
    const short* Bbase = BT + zoff + (size_t)n0 * ldbS
                         + ((MODE >= 1) ? (m0 & ~1023) : 0);
    const int c15 = lane & 15, g = lane >> 4, g4 = g * 4;
    const int xr0 = (c15 >> 1) & 3;
    const int srow = tid >> 2;
    const int schunk = (((tid & 3) ^ ((tid >> 3) & 3)) * 8);
    const int srowB = wid * 32 + (lane >> 2);
    const int schunkB = (((lane & 3) ^ ((lane >> 3) & 3)) * 8);

#define STG(s) do { \
    const int kc_ = (s) * 32; \
    const short* ga_ = Abase + (size_t)srow * ldaS + kc_ + schunk; \
    short* la_ = As + wid * 512; \
    gload_lds16(ga_, la_); \
    gload_lds16(ga_ + (size_t)64 * ldaS, la_ + 2048); \
    gload_lds16(ga_ + (size_t)128 * ldaS, la_ + 4096); \
    gload_lds16(ga_ + (size_t)192 * ldaS, la_ + 6144); \
    const short* gb_ = Bbase + (size_t)srowB * ldbS + kc_ + schunkB; \
    short* lb_ = Bs + wid * 1024; \
    gload_lds16(gb_, lb_); \
    gload_lds16(gb_ + (size_t)16 * ldbS, lb_ + 512); \
} while (0)

#define LDA_(mi) (*(const short8*)(As + (wm * 128 + (mi) * 16 + c15) * 32 + ((g ^ xr0) * 8)))
#define LDB_(nj) (*(const short8*)(Bs + (wn * 64 + (nj) * 16 + c15) * 32 + ((g ^ xr0) * 8)))

    f32x4 acc[8][4];
    #pragma unroll
    for (int i = 0; i < 8; ++i)
        #pragma unroll
        for (int j = 0; j < 4; ++j)
            acc[i][j] = (f32x4){0.f, 0.f, 0.f, 0.f};

    STG(0);

    for (int s = 0; s < Ksteps; ++s) {
        WAITV(0); SBAR(); SCHED0();
        short8 b0 = LDB_(0), b1 = LDB_(1), b2f = LDB_(2), b3 = LDB_(3);
        __builtin_amdgcn_s_setprio(1);
        #pragma unroll
        for (int mi = 0; mi < 8; ++mi) {
            short8 a = LDA_(mi);
            acc[mi][0] = __builtin_amdgcn_mfma_f32_16x16x32_bf16(a, b0, acc[mi][0], 0, 0, 0);
            acc[mi][1] = __builtin_amdgcn_mfma_f32_16x16x32_bf16(a, b1, acc[mi][1], 0, 0, 0);
            acc[mi][2] = __builtin_amdgcn_mfma_f32_16x16x32_bf16(a, b2f, acc[mi][2], 0, 0, 0);
            acc[mi][3] = __builtin_amdgcn_mfma_f32_16x16x32_bf16(a, b3, acc[mi][3], 0, 0, 0);
        }
        __builtin_amdgcn_s_setprio(0);
        SBAR();
        if (s + 1 < Ksteps) STG(s + 1);
    }

    float bv[4];
    #pragma unroll
    for (int nj = 0; nj < 4; ++nj)
        bv[nj] = bias ? bias[n0 + wn * 64 + nj * 16 + c15] : 0.f;
    #pragma unroll
    for (int mi = 0; mi < 8; ++mi) {
        #pragma unroll
        for (int r = 0; r < 4; ++r) {
            const size_t row = (size_t)m0 + wm * 128 + mi * 16 + g4 + r;
            #pragma unroll
            for (int nj = 0; nj < 4; ++nj) {
                const int col = n0 + wn * 64 + nj * 16 + c15;
                const float v = acc[mi][nj][r] + bv[nj];
                if (F32OUT) ((float*)Cout)[zoff + row * (size_t)ldc + col] = v;
                else        ((short*)Cout)[zoff + row * (size_t)ldc + col] = f2bf(v);
            }
        }
    }
#undef STG
#undef LDA_
#undef LDB_
}

// ---------------------------------------------------------------------------
// Per (head, block) causal attention. qkvh: [16384][3072] bf16, q at cols
// 0-1023, k at +1024, v at +2048 (col within each = h*64+e). obuf [16384][1024].
// r20: launch_bounds(256,3) -- 54,272 B LDS fits 3 blocks/CU (162,816 <=
// 163,840); cap regs at ~170 so occupancy isn't register-limited.
// ---------------------------------------------------------------------------
__global__ __launch_bounds__(256, 3) void attn_kernel(
    const short* __restrict__ qkvh, short* __restrict__ obuf)
{
    __shared__ __align__(16) char smem[54272];
    short* qs = (short*)smem;                 // [128][72]
    short* ks = (short*)smem + 9216;          // [128][72]
    short* vt = (short*)(smem + 36864);       // [64][136]  (v transposed)
    short* ps = (short*)smem;                 // [128][136] (reuses qs+ks region)
    short* os = (short*)smem;                 // [128][72]  (reused post-PV)

    const int tid = threadIdx.x, lane = tid & 63, wid = tid >> 6;
    const int h = blockIdx.x, b = blockIdx.y;
    const size_t base = (size_t)b * 128 * 3072 + (size_t)h * 64;

    for (int i = tid; i < 1024; i += 256) {
        const int row = i >> 3, c8 = i & 7;
        const size_t g = base + (size_t)row * 3072 + c8 * 8;
        *(short8*)(qs + row * 72 + c8 * 8) = *(const short8*)(qkvh + g);
        *(short8*)(ks + row * 72 + c8 * 8) = *(const short8*)(qkvh + g + 1024);
        short8 vv = *(const short8*)(qkvh + g + 2048);
        #pragma unroll
        for (int j = 0; j < 8; ++j) vt[(c8 * 8 + j) * 136 + row] = vv[j];
    }
    __syncthreads();

    const int c15 = lane & 15, g8 = (lane >> 4) * 8, g4 = (lane >> 4) * 4;
    const int r0 = wid * 32;

    f32x4 sacc[2][8];
    #pragma unroll
    for (int mi = 0; mi < 2; ++mi)
        #pragma unroll
        for (int nj = 0; nj < 8; ++nj)
            sacc[mi][nj] = (f32x4){0.f, 0.f, 0.f, 0.f};
    #pragma unroll
    for (int kk = 0; kk < 2; ++kk) {
        short8 aq[2];
        #pragma unroll
        for (int mi = 0; mi < 2; ++mi)
            aq[mi] = *(const short8*)(qs + (r0 + mi * 16 + c15) * 72 + kk * 32 + g8);
        #pragma unroll
        for (int nj = 0; nj < 8; ++nj) {
            short8 bk8 = *(const short8*)(ks + (nj * 16 + c15) * 72 + kk * 32 + g8);
            #pragma unroll
            for (int mi = 0; mi < 2; ++mi)
                sacc[mi][nj] = __builtin_amdgcn_mfma_f32_16x16x32_bf16(
                    aq[mi], bk8, sacc[mi][nj], 0, 0, 0);
        }
    }
    __syncthreads();

    #pragma unroll
    for (int mi = 0; mi < 2; ++mi) {
        #pragma unroll
        for (int r = 0; r < 4; ++r) {
            const int qrow = r0 + mi * 16 + g4 + r;
            float m = -3.0e38f, pv[8];
            #pragma unroll
            for (int nj = 0; nj < 8; ++nj) {
                float s = sacc[mi][nj][r] * 0.125f;
                if (nj * 16 + c15 > qrow) s = -1.0e9f;
                pv[nj] = s; m = fmaxf(m, s);
            }
            #pragma unroll
            for (int off = 8; off >= 1; off >>= 1) m = fmaxf(m, __shfl_xor(m, off));
            float sum = 0.f;
            #pragma unroll
            for (int nj = 0; nj < 8; ++nj) { float p = __expf(pv[nj] - m); pv[nj] = p; sum += p; }
            #pragma unroll
            for (int off = 8; off >= 1; off >>= 1) sum += __shfl_xor(sum, off);
            const float inv = 1.0f / sum;
            #pragma unroll
            for (int nj = 0; nj < 8; ++nj)
                ps[qrow * 136 + nj * 16 + c15] = f2bf(pv[nj] * inv);
        }
    }
    __syncthreads();

    f32x4 oacc[2][4];
    #pragma unroll
    for (int mi = 0; mi < 2; ++mi)
        #pragma unroll
        for (int nj = 0; nj < 4; ++nj)
            oacc[mi][nj] = (f32x4){0.f, 0.f, 0.f, 0.f};
    #pragma unroll
    for (int kt = 0; kt < 4; ++kt) {
        short8 ap[2];
        #pragma unroll
        for (int mi = 0; mi < 2; ++mi)
            ap[mi] = *(const short8*)(ps + (r0 + mi * 16 + c15) * 136 + kt * 32 + g8);
        #pragma unroll
        for (int nj = 0; nj < 4; ++nj) {
            short8 bv8 = *(const short8*)(vt + (nj * 16 + c15) * 136 + kt * 32 + g8);
            #pragma unroll
            for (int mi = 0; mi < 2; ++mi)
                oacc[mi][nj] = __builtin_amdgcn_mfma_f32_16x16x32_bf16(
                    ap[mi], bv8, oacc[mi][nj], 0, 0, 0);
        }
    }
    __syncthreads();

    #pragma unroll
    for (int mi = 0; mi < 2; ++mi)
        #pragma unroll
        for (int r = 0; r < 4; ++r)
            #pragma unroll
            for (int nj = 0; nj < 4; ++nj)
                os[(r0 + mi * 16 + g4 + r) * 72 + nj * 16 + c15] = f2bf(oacc[mi][nj][r]);
    __syncthreads();

    for (int i = tid; i < 1024; i += 256) {
        const int row = i >> 3, c8 = i & 7;
        *(short8*)(obuf + (size_t)b * 128 * 1024 + (size_t)h * 64
                   + (size_t)row * 1024 + c8 * 8) =
            *(const short8*)(os + row * 72 + c8 * 8);
    }
}

// ---------------------------------------------------------------------------
__global__ void pad_convert_inputs(const float* __restrict__ in, short* __restrict__ out)
{
    const int row = blockIdx.x;                 // [0, 16388)
    const int n = row / 8194, l = row % 8194;
    short* orow = out + (size_t)row * 4096;
    if (l == 0 || l == 8193) {
        for (int i = threadIdx.x; i < 512; i += 256) {
            uint4 z; z.x = z.y = z.z = z.w = 0u;
            *(uint4*)(orow + i * 8) = z;
        }
    } else {
        const float* irow = in + ((size_t)n * 8192 + (l - 1)) * 4096;
        for (int i = threadIdx.x; i < 512; i += 256) {
            float4 a = *(const float4*)(irow + i * 8);
            float4 b = *(const float4*)(irow + i * 8 + 4);
            short8 v;
            v[0] = f2bf(a.x); v[1] = f2bf(a.y); v[2] = f2bf(a.z); v[3] = f2bf(a.w);
            v[4] = f2bf(b.x); v[5] = f2bf(b.y); v[6] = f2bf(b.z); v[7] = f2bf(b.w);
            *(short8*)(orow + i * 8) = v;
        }
    }
}

__global__ void transpose_convert(const float* __restrict__ in, short* __restrict__ out,
                                  int R, int C)
{
    __shared__ float tile[32][33];
    const int tx = threadIdx.x & 31, ty = threadIdx.x >> 5;   // 32 x 8
    const int bx = blockIdx.x * 32, by = blockIdx.y * 32;
    #pragma unroll
    for (int i = 0; i < 32; i += 8)
        tile[ty + i][tx] = in[(size_t)(by + ty + i) * C + bx + tx];
    __syncthreads();
    #pragma unroll
    for (int i = 0; i < 32; i += 8)
        out[(size_t)(bx + ty + i) * R + by + tx] = f2bf(tile[tx][ty + i]);
}

__global__ void convert_bf16(const float* __restrict__ in, short* __restrict__ out, int n8)
{
    const int idx = blockIdx.x * 256 + threadIdx.x;
    if (idx < n8) {
        float4 a = *(const float4*)(in + (size_t)idx * 8);
        float4 b = *(const float4*)(in + (size_t)idx * 8 + 4);
        short8 v;
        v[0] = f2bf(a.x); v[1] = f2bf(a.y); v[2] = f2bf(a.z); v[3] = f2bf(a.w);
        v[4] = f2bf(b.x); v[5] = f2bf(b.y); v[6] = f2bf(b.z); v[7] = f2bf(b.w);
        *(short8*)(out + (size_t)idx * 8) = v;
    }
}

// bfused[j] = proj_b[j] + sum_w bo[w]*proj_w[w][j] -- split-K (r19): 16
// outputs per 256-thread block, 16 lanes x 64 terms, shfl_xor reduce.
__global__ void fuse_bias(const float* __restrict__ bo, const float* __restrict__ projw,
                          const float* __restrict__ projb, float* __restrict__ outb)
{
    const int tid = threadIdx.x;
    const int j = blockIdx.x * 16 + (tid >> 4);     // 4096 outputs
    const int sub = tid & 15;
    float s = 0.f;
    const int w0 = sub * 64;
    for (int w = w0; w < w0 + 64; ++w)
        s = fmaf(bo[w], projw[(size_t)w * 4096 + j], s);
    #pragma unroll
    for (int off = 8; off >= 1; off >>= 1) s += __shfl_xor(s, off);
    if (sub == 0) outb[j] = s + projb[j];
}

// b2[o] = b_part[o&1023] + sum_d conv_b[(o>>10)*1024+d]*wpart[d][o&1023]
__global__ void fuse_bias_qkv(const float* __restrict__ conv_b,
                              const float* __restrict__ wq, const float* __restrict__ bq,
                              const float* __restrict__ wk, const float* __restrict__ bk,
                              const float* __restrict__ wv, const float* __restrict__ bv,
                              float* __restrict__ outb)
{
    const int tid = threadIdx.x;
    const int o = blockIdx.x * 16 + (tid >> 4);     // 3072 outputs
    const int sub = tid & 15;
    const int p = o >> 10, e = o & 1023;
    const float* w = (p == 0) ? wq : (p == 1) ? wk : wv;
    const float* bb = (p == 0) ? bq : (p == 1) ? bk : bv;
    const float* cb = conv_b + p * 1024;
    float s = 0.f;
    const int d0 = sub * 64;
    for (int d = d0; d < d0 + 64; ++d)
        s = fmaf(cb[d], w[(size_t)d * 1024 + e], s);
    #pragma unroll
    for (int off = 8; off >= 1; off >>= 1) s += __shfl_xor(s, off);
    if (sub == 0) outb[o] = s + bb[e];
}

// ---------------------------------------------------------------------------
extern "C" void kernel_launch(void* const* d_in, const int* in_sizes, int n_in,
                              void* d_out, int out_size, void* d_ws, size_t ws_size,
                              hipStream_t stream)
{
    const float* inputs = (const float*)d_in[0];
    const float* conv_w = (const float*)d_in[1];
    const float* conv_b = (const float*)d_in[2];
    const float* wq     = (const float*)d_in[3];
    const float* bq     = (const float*)d_in[4];
    const float* wk     = (const float*)d_in[5];
    const float* bk     = (const float*)d_in[6];
    const float* wv     = (const float*)d_in[7];
    const float* bv     = (const float*)d_in[8];
    const float* wo     = (const float*)d_in[9];
    const float* bo     = (const float*)d_in[10];
    const float* proj_w = (const float*)d_in[11];
    const float* proj_b = (const float*)d_in[12];

    char* ws = (char*)d_ws;
    short* in_pad = (short*)(ws + 0);             // [2][8194][4096]      134,283,264 B
    short* cw_bf  = (short*)(ws + 134283264);     // [3][4096][3072] bf16 (dead after prep)
    short* qkvh   = (short*)(ws + 134283264);     // [16384][3072] over cw_bf
    short* W2T    = (short*)(ws + 234946560);     // [3][3072][4096] bf16
    short* wq_t   = (short*)(ws + 310444032);     // [3][1024][1024] BT contiguous
    short* wo_bf  = (short*)(ws + 316735488);     // [1024][1024]
    short* proj_t = (short*)(ws + 318832640);     // [4096][1024]
    short* WfT    = (short*)(ws + 327221248);     // [4096][1024]
    float* bfused = (float*)(ws + 335609856);     // [4096]
    float* b2     = (float*)(ws + 335626240);     // [3072]
    short* o_buf  = (short*)(ws + 0);             // [16384][1024] over in_pad

    dim3 blk(256);

    pad_convert_inputs<<<16388, blk, 0, stream>>>(inputs, in_pad);
    convert_bf16<<<18432, blk, 0, stream>>>(conv_w, cw_bf, 4718592);   // straight convert
    transpose_convert<<<dim3(32, 32), blk, 0, stream>>>(wq, wq_t, 1024, 1024);
    transpose_convert<<<dim3(32, 32), blk, 0, stream>>>(wk, wq_t + 1048576, 1024, 1024);
    transpose_convert<<<dim3(32, 32), blk, 0, stream>>>(wv, wq_t + 2097152, 1024, 1024);
    transpose_convert<<<dim3(128, 32), blk, 0, stream>>>(proj_w, proj_t, 1024, 4096);
    convert_bf16<<<512, blk, 0, stream>>>(wo, wo_bf, 131072);
    fuse_bias<<<256, blk, 0, stream>>>(bo, proj_w, proj_b, bfused);
    fuse_bias_qkv<<<192, blk, 0, stream>>>(conv_b, wq, bq, wk, bk, wv, bv, b2);

    // WfT[dm][he] = sum_w proj_t[dm][w] * wo_flat[he][w]
    gemm128<0, false><<<dim3(8, 16), blk, 0, stream>>>(
        proj_t, 1024, wo_bf, 1024, WfT, 1024, nullptr, 32);
    // weight prep (merged, r20): W2T[z][o][i] = sum_d wqkvT[o][d]*conv_w[z][i][..]
    gemm128<2, false><<<dim3(32, 12, 3), blk, 0, stream>>>(
        wq_t, 1024, cw_bf, 3072, W2T, 4096, nullptr, 32);
    // fused conv+projection, tap-shared A, 3 blocks/CU -> qkvh [16384][3072]
    conv3_gemm<<<dim3(24, 64), blk, 0, stream>>>(in_pad, W2T, qkvh, b2);

    attn_kernel<<<dim3(16, 128), blk, 0, stream>>>(qkvh, o_buf);

    // out = o @ Wf + bfused   (f32 out)
    gemm128<0, true><<<dim3(32, 64), blk, 0, stream>>>(
        o_buf, 1024, WfT, 1024, d_out, 4096, bfused, 32);
}